// Round 1
// baseline (938.615 us; speedup 1.0000x reference)
//
#include <hip/hip_runtime.h>
#include <math.h>

#define CC 256
#define LT 8
#define LHH 32
#define LWW 32
#define LL 8192          // LT*LHH*LWW
#define NBATCH 2         // T*B
#define RR 32            // regions
#define PPP 256          // voxels per region
#define NTOP 4
#define NHEAD 8
#define DHEAD 32
#define MTOT 16384       // NBATCH*LL

// ---------------- BN stats (per-channel mean / inv-std over T,B,spatial) ----------------
__global__ __launch_bounds__(256) void k_bnstats(const float* __restrict__ x,
                                                 float* __restrict__ mean,
                                                 float* __restrict__ istd) {
  int c = blockIdx.x, tid = threadIdx.x;
  float s = 0.f, sq = 0.f;
  for (int i = tid; i < NBATCH * LL; i += 256) {
    int t = i >> 13, l = i & (LL - 1);
    float v = x[(t * CC + c) * LL + l];
    s += v; sq += v * v;
  }
  __shared__ float rs[256], rq[256];
  rs[tid] = s; rq[tid] = sq;
  __syncthreads();
  for (int off = 128; off > 0; off >>= 1) {
    if (tid < off) { rs[tid] += rs[tid + off]; rq[tid] += rq[tid + off]; }
    __syncthreads();
  }
  if (tid == 0) {
    float m = rs[0] * (1.f / (NBATCH * LL));
    float var = rq[0] * (1.f / (NBATCH * LL)) - m * m;
    mean[c] = m;
    istd[c] = rsqrtf(var + 1e-5f);
  }
}

// ---------------- BN apply + 2-step LIF; spikes written in [t][c][l] layout ----------------
__global__ __launch_bounds__(256) void k_lif(const float* __restrict__ xin,
                                             const float* __restrict__ mean,
                                             const float* __restrict__ istd,
                                             const float* __restrict__ g,
                                             const float* __restrict__ b,
                                             float* __restrict__ spk) {
  int i = blockIdx.x * 256 + threadIdx.x;   // over CC*LL
  int c = i >> 13;
  float m = mean[c], is = istd[c], gg = g[c], bb = b[c];
  float x0 = xin[i];
  float x1 = xin[CC * LL + i];
  float y0 = gg * (x0 - m) * is + bb;
  float y1 = gg * (x1 - m) * is + bb;
  float v = 0.f;
  v += (y0 - v) * 0.5f;
  float s0 = (v >= 1.f) ? 1.f : 0.f;
  v -= s0;
  v += (y1 - v) * 0.5f;
  float s1 = (v >= 1.f) ? 1.f : 0.f;
  spk[i] = s0;
  spk[CC * LL + i] = s1;
}

// ---------------- qkv GEMM (TN: A stored [n][k][l]) + scatter into region layout ----------------
__global__ __launch_bounds__(256) void k_gemm_qkv(const float* __restrict__ A,
                                                  const float* __restrict__ W,
                                                  const float* __restrict__ bias,
                                                  float* __restrict__ qr,
                                                  float* __restrict__ kr,
                                                  float* __restrict__ vr) {
  const int BN = 768;
  __shared__ __align__(16) float As[16][64];
  __shared__ __align__(16) float Bs[16][64];
  int tid = threadIdx.x;
  int tx = tid & 15, ty = tid >> 4;
  int j0 = blockIdx.x * 64, m0 = blockIdx.y * 64;
  int n = m0 >> 13, l0 = m0 & (LL - 1);
  float acc[4][4] = {};
  int ka = tid >> 4, ma = (tid & 15) * 4;
  for (int k0 = 0; k0 < CC; k0 += 16) {
    *(float4*)&As[ka][ma] = *(const float4*)&A[(n * CC + k0 + ka) * LL + l0 + ma];
    *(float4*)&Bs[ka][ma] = *(const float4*)&W[(k0 + ka) * BN + j0 + ma];
    __syncthreads();
#pragma unroll
    for (int k = 0; k < 16; ++k) {
      float4 av = *(const float4*)&As[k][ty * 4];
      float4 bv = *(const float4*)&Bs[k][tx * 4];
      float a[4] = {av.x, av.y, av.z, av.w};
      float bb[4] = {bv.x, bv.y, bv.z, bv.w};
#pragma unroll
      for (int i = 0; i < 4; ++i)
#pragma unroll
        for (int j = 0; j < 4; ++j) acc[i][j] = fmaf(a[i], bb[j], acc[i][j]);
    }
    __syncthreads();
  }
#pragma unroll
  for (int i = 0; i < 4; ++i) {
    int mrow = m0 + ty * 4 + i;
    int l = mrow & (LL - 1);
    int lt = l >> 10, lh = (l >> 5) & 31, lw = l & 31;
    int r = ((lt >> 2) * 4 + (lh >> 3)) * 4 + (lw >> 3);
    int p = ((lt & 3) * 8 + (lh & 7)) * 8 + (lw & 7);
    int base = ((n * RR + r) * PPP + p) * CC;
#pragma unroll
    for (int jj = 0; jj < 4; ++jj) {
      int j = j0 + tx * 4 + jj;
      float val = acc[i][jj] + bias[j];
      int which = j >> 8, ch = j & 255;
      float* dst = (which == 0) ? qr : ((which == 1) ? kr : vr);
      dst[base + ch] = val;
    }
  }
}

// ---------------- region means of q and k ----------------
__global__ __launch_bounds__(256) void k_means(const float* __restrict__ qr,
                                               const float* __restrict__ kr,
                                               float* __restrict__ qm,
                                               float* __restrict__ km) {
  int nr = blockIdx.x;
  int c = threadIdx.x;
  int base = nr * PPP * CC + c;
  float sq = 0.f, sk = 0.f;
  for (int p = 0; p < PPP; ++p) {
    sq += qr[base + p * CC];
    sk += kr[base + p * CC];
  }
  qm[nr * CC + c] = sq * (1.f / PPP);
  km[nr * CC + c] = sk * (1.f / PPP);
}

// ---------------- routing scores + top-4 ----------------
__global__ __launch_bounds__(64) void k_route(const float* __restrict__ qm,
                                              const float* __restrict__ km,
                                              int* __restrict__ idx) {
  int nr = blockIdx.x;
  int n = nr >> 5;
  int tid = threadIdx.x;
  __shared__ float ar[32];
  if (tid < 32) {
    const float* qrow = qm + nr * CC;
    const float* krow = km + (n * RR + tid) * CC;
    float s = 0.f;
    for (int c = 0; c < CC; ++c) s += qrow[c] * krow[c];
    ar[tid] = s;
  }
  __syncthreads();
  if (tid == 0) {
    for (int t = 0; t < NTOP; ++t) {
      float best = -1e30f; int bi = 0;
      for (int s = 0; s < 32; ++s)
        if (ar[s] > best) { best = ar[s]; bi = s; }
      ar[bi] = -1e30f;
      idx[nr * NTOP + t] = bi;
    }
  }
}

// ---------------- flash-style attention per (n, region, head) ----------------
__global__ __launch_bounds__(128) void k_attn(const float* __restrict__ qr,
                                              const float* __restrict__ kr,
                                              const float* __restrict__ vr,
                                              const int* __restrict__ idx,
                                              float* __restrict__ oreg) {
  int h = blockIdx.x, r = blockIdx.y, n = blockIdx.z;
  int tid = threadIdx.x;
  __shared__ float4 ks4[1024];   // 128 rows x 8 float4 (32 ch)
  __shared__ float4 vs4[1024];
  const float qs = 0.17677669529663687f;   // 32^-0.5
  float4 q0[8], q1[8], o0[8], o1[8];
  int qbase = ((n * RR + r) * PPP) * CC + h * DHEAD;
#pragma unroll
  for (int d = 0; d < 8; ++d) {
    float4 t0 = *(const float4*)&qr[qbase + tid * CC + d * 4];
    float4 t1 = *(const float4*)&qr[qbase + (tid + 128) * CC + d * 4];
    q0[d] = make_float4(t0.x * qs, t0.y * qs, t0.z * qs, t0.w * qs);
    q1[d] = make_float4(t1.x * qs, t1.y * qs, t1.z * qs, t1.w * qs);
    o0[d] = make_float4(0.f, 0.f, 0.f, 0.f);
    o1[d] = make_float4(0.f, 0.f, 0.f, 0.f);
  }
  float l0 = 0.f, l1 = 0.f;
  for (int ki = 0; ki < NTOP; ++ki) {
    int reg = idx[(n * RR + r) * NTOP + ki];
    int kb = ((n * RR + reg) * PPP) * CC + h * DHEAD;
    for (int half = 0; half < 2; ++half) {
      __syncthreads();
#pragma unroll
      for (int i = 0; i < 8; ++i) {
        int lin = i * 128 + tid;
        int row = lin >> 3, d4 = lin & 7;
        int ga = kb + (half * 128 + row) * CC + d4 * 4;
        ks4[lin] = *(const float4*)&kr[ga];
        vs4[lin] = *(const float4*)&vr[ga];
      }
      __syncthreads();
      for (int kk = 0; kk < 128; ++kk) {
        const float4* krow = &ks4[kk * 8];
        float d0[8], d1[8];
#pragma unroll
        for (int d = 0; d < 8; ++d) {
          float4 kf = krow[d];
          d0[d] = q0[d].x * kf.x + q0[d].y * kf.y + q0[d].z * kf.z + q0[d].w * kf.w;
          d1[d] = q1[d].x * kf.x + q1[d].y * kf.y + q1[d].z * kf.z + q1[d].w * kf.w;
        }
        float s0 = ((d0[0] + d0[1]) + (d0[2] + d0[3])) + ((d0[4] + d0[5]) + (d0[6] + d0[7]));
        float s1 = ((d1[0] + d1[1]) + (d1[2] + d1[3])) + ((d1[4] + d1[5]) + (d1[6] + d1[7]));
        float p0 = __expf(s0), p1 = __expf(s1);
        l0 += p0; l1 += p1;
        const float4* vrow = &vs4[kk * 8];
#pragma unroll
        for (int d = 0; d < 8; ++d) {
          float4 vf = vrow[d];
          o0[d].x = fmaf(p0, vf.x, o0[d].x);
          o0[d].y = fmaf(p0, vf.y, o0[d].y);
          o0[d].z = fmaf(p0, vf.z, o0[d].z);
          o0[d].w = fmaf(p0, vf.w, o0[d].w);
          o1[d].x = fmaf(p1, vf.x, o1[d].x);
          o1[d].y = fmaf(p1, vf.y, o1[d].y);
          o1[d].z = fmaf(p1, vf.z, o1[d].z);
          o1[d].w = fmaf(p1, vf.w, o1[d].w);
        }
      }
    }
  }
  float inv0 = 1.f / l0, inv1 = 1.f / l1;
  int ob0 = ((n * RR + r) * PPP + tid) * CC + h * DHEAD;
  int ob1 = ((n * RR + r) * PPP + tid + 128) * CC + h * DHEAD;
#pragma unroll
  for (int d = 0; d < 8; ++d) {
    float4 w0 = make_float4(o0[d].x * inv0, o0[d].y * inv0, o0[d].z * inv0, o0[d].w * inv0);
    float4 w1 = make_float4(o1[d].x * inv1, o1[d].y * inv1, o1[d].z * inv1, o1[d].w * inv1);
    *(float4*)&oreg[ob0 + d * 4] = w0;
    *(float4*)&oreg[ob1 + d * 4] = w1;
  }
}

// ---------------- from_reg + LEPE depthwise 3x3x3 -> token layout ----------------
__global__ __launch_bounds__(256) void k_lepe(const float* __restrict__ oreg,
                                              const float* __restrict__ vr,
                                              const float* __restrict__ w,
                                              float* __restrict__ otok) {
  int blk = blockIdx.x;                 // n*256 + lt*32 + lh
  int lh = blk & 31, lt = (blk >> 5) & 7, n = blk >> 8;
  int c = threadIdx.x;
  __shared__ float wl[27 * 256];
  for (int i = threadIdx.x; i < 27 * 256; i += 256) {
    int cc = i / 27, tp = i % 27;
    wl[tp * 256 + cc] = w[i];
  }
  __syncthreads();
  for (int lw = 0; lw < 32; ++lw) {
    int r = ((lt >> 2) * 4 + (lh >> 3)) * 4 + (lw >> 3);
    int p = ((lt & 3) * 8 + (lh & 7)) * 8 + (lw & 7);
    float acc = oreg[((n * RR + r) * PPP + p) * CC + c];
    float lep = 0.f;
    for (int dz = -1; dz <= 1; ++dz) {
      int z = lt + dz;
      if (z < 0 || z >= LT) continue;
      for (int dy = -1; dy <= 1; ++dy) {
        int y = lh + dy;
        if (y < 0 || y >= LHH) continue;
        for (int dx = -1; dx <= 1; ++dx) {
          int xx = lw + dx;
          if (xx < 0 || xx >= LWW) continue;
          int r2 = ((z >> 2) * 4 + (y >> 3)) * 4 + (xx >> 3);
          int p2 = ((z & 3) * 8 + (y & 7)) * 8 + (xx & 7);
          int tap = ((dz + 1) * 3 + (dy + 1)) * 3 + (dx + 1);
          lep = fmaf(wl[tap * 256 + c], vr[((n * RR + r2) * PPP + p2) * CC + c], lep);
        }
      }
    }
    int l = (lt * 32 + lh) * 32 + lw;
    otok[(n * LL + l) * CC + c] = acc + lep;
  }
}

// ---------------- Wo GEMM (NN) ; out = x + (A@Wo + bo) * scale ----------------
__global__ __launch_bounds__(256) void k_gemm_wo(const float* __restrict__ A,
                                                 const float* __restrict__ W,
                                                 const float* __restrict__ bias,
                                                 const float* __restrict__ xin,
                                                 const float* __restrict__ scale,
                                                 float* __restrict__ out) {
  const int BN = 256, K = 256;
  __shared__ __align__(16) float As[16][64];
  __shared__ __align__(16) float Bs[16][64];
  int tid = threadIdx.x;
  int tx = tid & 15, ty = tid >> 4;
  int j0 = blockIdx.x * 64, m0 = blockIdx.y * 64;
  float acc[4][4] = {};
  int ka = tid >> 4, ja = (tid & 15) * 4;
  int mA = tid >> 2, kA = (tid & 3) * 4;
  for (int k0 = 0; k0 < K; k0 += 16) {
    float4 af = *(const float4*)&A[(m0 + mA) * K + k0 + kA];
    As[kA + 0][mA] = af.x; As[kA + 1][mA] = af.y; As[kA + 2][mA] = af.z; As[kA + 3][mA] = af.w;
    *(float4*)&Bs[ka][ja] = *(const float4*)&W[(k0 + ka) * BN + j0 + ja];
    __syncthreads();
#pragma unroll
    for (int k = 0; k < 16; ++k) {
      float4 av = *(const float4*)&As[k][ty * 4];
      float4 bv = *(const float4*)&Bs[k][tx * 4];
      float a[4] = {av.x, av.y, av.z, av.w};
      float bb[4] = {bv.x, bv.y, bv.z, bv.w};
#pragma unroll
      for (int i = 0; i < 4; ++i)
#pragma unroll
        for (int j = 0; j < 4; ++j) acc[i][j] = fmaf(a[i], bb[j], acc[i][j]);
    }
    __syncthreads();
  }
  float sc = scale[0];
#pragma unroll
  for (int i = 0; i < 4; ++i) {
    int mrow = m0 + ty * 4 + i;
    int t = mrow >> 13, l = mrow & (LL - 1);
#pragma unroll
    for (int jj = 0; jj < 4; ++jj) {
      int ch = j0 + tx * 4 + jj;
      int oi = (t * CC + ch) * LL + l;
      out[oi] = xin[oi] + (acc[i][jj] + bias[ch]) * sc;
    }
  }
}

// ---------------- FFN GEMM1 (TN) with exact GELU ----------------
__global__ __launch_bounds__(256) void k_gemm_ffn1(const float* __restrict__ A,
                                                   const float* __restrict__ W,
                                                   const float* __restrict__ bias,
                                                   float* __restrict__ hbuf) {
  const int BN = 1024;
  __shared__ __align__(16) float As[16][64];
  __shared__ __align__(16) float Bs[16][64];
  int tid = threadIdx.x;
  int tx = tid & 15, ty = tid >> 4;
  int j0 = blockIdx.x * 64, m0 = blockIdx.y * 64;
  int n = m0 >> 13, l0 = m0 & (LL - 1);
  float acc[4][4] = {};
  int ka = tid >> 4, ma = (tid & 15) * 4;
  for (int k0 = 0; k0 < CC; k0 += 16) {
    *(float4*)&As[ka][ma] = *(const float4*)&A[(n * CC + k0 + ka) * LL + l0 + ma];
    *(float4*)&Bs[ka][ma] = *(const float4*)&W[(k0 + ka) * BN + j0 + ma];
    __syncthreads();
#pragma unroll
    for (int k = 0; k < 16; ++k) {
      float4 av = *(const float4*)&As[k][ty * 4];
      float4 bv = *(const float4*)&Bs[k][tx * 4];
      float a[4] = {av.x, av.y, av.z, av.w};
      float bb[4] = {bv.x, bv.y, bv.z, bv.w};
#pragma unroll
      for (int i = 0; i < 4; ++i)
#pragma unroll
        for (int j = 0; j < 4; ++j) acc[i][j] = fmaf(a[i], bb[j], acc[i][j]);
    }
    __syncthreads();
  }
#pragma unroll
  for (int i = 0; i < 4; ++i) {
    int mrow = m0 + ty * 4 + i;
#pragma unroll
    for (int jj = 0; jj < 4; ++jj) {
      int j = j0 + tx * 4 + jj;
      float z = acc[i][jj] + bias[j];
      float gel = 0.5f * z * (1.f + erff(z * 0.70710678118654752f));
      hbuf[mrow * 1024 + j] = gel;
    }
  }
}

// ---------------- FFN GEMM2 (NN, K=1024); out += (A@W2 + b2) * scale ----------------
__global__ __launch_bounds__(256) void k_gemm_ffn2(const float* __restrict__ A,
                                                   const float* __restrict__ W,
                                                   const float* __restrict__ bias,
                                                   const float* __restrict__ scale,
                                                   float* __restrict__ out) {
  const int BN = 256, K = 1024;
  __shared__ __align__(16) float As[16][64];
  __shared__ __align__(16) float Bs[16][64];
  int tid = threadIdx.x;
  int tx = tid & 15, ty = tid >> 4;
  int j0 = blockIdx.x * 64, m0 = blockIdx.y * 64;
  float acc[4][4] = {};
  int ka = tid >> 4, ja = (tid & 15) * 4;
  int mA = tid >> 2, kA = (tid & 3) * 4;
  for (int k0 = 0; k0 < K; k0 += 16) {
    float4 af = *(const float4*)&A[(m0 + mA) * K + k0 + kA];
    As[kA + 0][mA] = af.x; As[kA + 1][mA] = af.y; As[kA + 2][mA] = af.z; As[kA + 3][mA] = af.w;
    *(float4*)&Bs[ka][ja] = *(const float4*)&W[(k0 + ka) * BN + j0 + ja];
    __syncthreads();
#pragma unroll
    for (int k = 0; k < 16; ++k) {
      float4 av = *(const float4*)&As[k][ty * 4];
      float4 bv = *(const float4*)&Bs[k][tx * 4];
      float a[4] = {av.x, av.y, av.z, av.w};
      float bb[4] = {bv.x, bv.y, bv.z, bv.w};
#pragma unroll
      for (int i = 0; i < 4; ++i)
#pragma unroll
        for (int j = 0; j < 4; ++j) acc[i][j] = fmaf(a[i], bb[j], acc[i][j]);
    }
    __syncthreads();
  }
  float sc = scale[0];
#pragma unroll
  for (int i = 0; i < 4; ++i) {
    int mrow = m0 + ty * 4 + i;
    int t = mrow >> 13, l = mrow & (LL - 1);
#pragma unroll
    for (int jj = 0; jj < 4; ++jj) {
      int ch = j0 + tx * 4 + jj;
      int oi = (t * CC + ch) * LL + l;
      out[oi] += (acc[i][jj] + bias[ch]) * sc;
    }
  }
}

extern "C" void kernel_launch(void* const* d_in, const int* in_sizes, int n_in,
                              void* d_out, int out_size, void* d_ws, size_t ws_size,
                              hipStream_t stream) {
  const float* x      = (const float*)d_in[0];
  const float* bn1_g  = (const float*)d_in[1];
  const float* bn1_b  = (const float*)d_in[2];
  const float* wqkv   = (const float*)d_in[3];
  const float* bqkv   = (const float*)d_in[4];
  const float* lepe_w = (const float*)d_in[5];
  const float* wo_w   = (const float*)d_in[6];
  const float* bo     = (const float*)d_in[7];
  const float* bn2_g  = (const float*)d_in[8];
  const float* bn2_b  = (const float*)d_in[9];
  const float* ffn_w1 = (const float*)d_in[10];
  const float* ffn_b1 = (const float*)d_in[11];
  const float* ffn_w2 = (const float*)d_in[12];
  const float* ffn_b2 = (const float*)d_in[13];
  const float* scale  = (const float*)d_in[14];
  float* out = (float*)d_out;

  float* ws   = (float*)d_ws;
  float* spk  = ws;                       // 4,194,304 (reused as s2)
  float* qr   = ws + 4194304;             // 4,194,304
  float* kr   = ws + 8388608;
  float* vr   = ws + 12582912;
  float* oreg = ws + 16777216;
  float* otok = ws + 20971520;
  float* hbuf = ws + 4194304;             // 16,777,216 floats, overlaps qr..oreg (dead then)
  float* sm    = ws + 25165824;
  float* mean1 = sm;
  float* istd1 = sm + 256;
  float* mean2 = sm + 512;
  float* istd2 = sm + 768;
  float* qm    = sm + 1024;
  float* km    = sm + 1024 + 16384;
  int*   idxb  = (int*)(sm + 1024 + 32768);

  // ---- attention branch ----
  k_bnstats<<<256, 256, 0, stream>>>(x, mean1, istd1);
  k_lif<<<8192, 256, 0, stream>>>(x, mean1, istd1, bn1_g, bn1_b, spk);
  k_gemm_qkv<<<dim3(12, 256), 256, 0, stream>>>(spk, wqkv, bqkv, qr, kr, vr);
  k_means<<<64, 256, 0, stream>>>(qr, kr, qm, km);
  k_route<<<64, 64, 0, stream>>>(qm, km, idxb);
  k_attn<<<dim3(NHEAD, RR, NBATCH), 128, 0, stream>>>(qr, kr, vr, idxb, oreg);
  k_lepe<<<512, 256, 0, stream>>>(oreg, vr, lepe_w, otok);
  k_gemm_wo<<<dim3(4, 256), 256, 0, stream>>>(otok, wo_w, bo, x, scale, out);

  // ---- FFN branch ----
  k_bnstats<<<256, 256, 0, stream>>>(out, mean2, istd2);
  k_lif<<<8192, 256, 0, stream>>>(out, mean2, istd2, bn2_g, bn2_b, spk);
  k_gemm_ffn1<<<dim3(16, 256), 256, 0, stream>>>(spk, ffn_w1, ffn_b1, hbuf);
  k_gemm_ffn2<<<dim3(4, 256), 256, 0, stream>>>(hbuf, ffn_w2, ffn_b2, scale, out);
}

// Round 2
// 611.097 us; speedup vs baseline: 1.5360x; 1.5360x over previous
//
#include <hip/hip_runtime.h>
#include <math.h>

#define CC 256
#define LL 8192
#define RR 32
#define PPP 256
#define NTOP 4

typedef unsigned short u16;
typedef __attribute__((ext_vector_type(8))) short short8;
typedef __attribute__((ext_vector_type(4))) float f32x4;

__device__ inline u16 f2bf(float f) {
  unsigned int b = __float_as_uint(f);
  unsigned int r = (b + 0x7FFFu + ((b >> 16) & 1u)) >> 16;
  return (u16)r;
}

// ---------------- BN stats ----------------
__global__ __launch_bounds__(256) void k_bnstats(const float* __restrict__ x,
                                                 float* __restrict__ mean,
                                                 float* __restrict__ istd) {
  int c = blockIdx.x, tid = threadIdx.x;
  float s = 0.f, sq = 0.f;
  for (int i = tid; i < 2 * LL; i += 256) {
    int t = i >> 13, l = i & (LL - 1);
    float v = x[(t * CC + c) * LL + l];
    s += v; sq += v * v;
  }
  __shared__ float rs[256], rq[256];
  rs[tid] = s; rq[tid] = sq;
  __syncthreads();
  for (int off = 128; off > 0; off >>= 1) {
    if (tid < off) { rs[tid] += rs[tid + off]; rq[tid] += rq[tid + off]; }
    __syncthreads();
  }
  if (tid == 0) {
    float m = rs[0] * (1.f / (2 * LL));
    float var = rq[0] * (1.f / (2 * LL)) - m * m;
    mean[c] = m;
    istd[c] = rsqrtf(var + 1e-5f);
  }
}

// ---------------- BN + 2-step LIF -> spikes [t][c][l] fp32 ----------------
__global__ __launch_bounds__(256) void k_lif(const float* __restrict__ xin,
                                             const float* __restrict__ mean,
                                             const float* __restrict__ istd,
                                             const float* __restrict__ g,
                                             const float* __restrict__ b,
                                             float* __restrict__ spk) {
  int i = blockIdx.x * 256 + threadIdx.x;
  int c = i >> 13;
  float m = mean[c], is = istd[c], gg = g[c], bb = b[c];
  float x0 = xin[i];
  float x1 = xin[CC * LL + i];
  float y0 = gg * (x0 - m) * is + bb;
  float y1 = gg * (x1 - m) * is + bb;
  float v = 0.f;
  v += (y0 - v) * 0.5f;
  float s0 = (v >= 1.f) ? 1.f : 0.f;
  v -= s0;
  v += (y1 - v) * 0.5f;
  float s1 = (v >= 1.f) ? 1.f : 0.f;
  spk[i] = s0;
  spk[CC * LL + i] = s1;
}

// ---------------- generic fp32 [R][C] -> bf16 [C][R] transpose (batched via z) ----------------
__global__ __launch_bounds__(256) void k_tr(const float* __restrict__ in, u16* __restrict__ out,
                                            int R, int C, long ibs, long obs) {
  __shared__ float t[32][33];
  const float* ib = in + (size_t)blockIdx.z * ibs;
  u16* ob = out + (size_t)blockIdx.z * obs;
  int c0 = blockIdx.x * 32, r0 = blockIdx.y * 32;
  int tx = threadIdx.x & 31, ty = threadIdx.x >> 5;
  for (int i = 0; i < 32; i += 8)
    t[ty + i][tx] = ib[(size_t)(r0 + ty + i) * C + c0 + tx];
  __syncthreads();
  for (int i = 0; i < 32; i += 8)
    ob[(size_t)(c0 + ty + i) * R + r0 + tx] = f2bf(t[tx][ty + i]);
}

// ---------------- MFMA core: D[m][n] += A[m][k]*B[n][k]^T, K-contiguous bf16 operands ----------------
template<int MR, int NR, int WCN>
__device__ inline void mfma_core(const u16* __restrict__ A0, int sA,
                                 const u16* __restrict__ B0, int sB,
                                 int K, f32x4 acc[MR][NR]) {
  int lane = threadIdx.x & 63;
  int w = threadIdx.x >> 6;
  int wr = w / WCN, wc = w % WCN;
  int rr = lane & 15;
  int g8 = (lane >> 4) * 8;
  const u16* Ap = A0 + (size_t)(wr * MR * 16 + rr) * sA + g8;
  const u16* Bp = B0 + (size_t)(wc * NR * 16 + rr) * sB + g8;
  for (int k0 = 0; k0 < K; k0 += 32) {
    short8 af[MR], bfr[NR];
#pragma unroll
    for (int i = 0; i < MR; ++i)
      af[i] = *(const short8*)(Ap + (size_t)i * 16 * sA + k0);
#pragma unroll
    for (int j = 0; j < NR; ++j)
      bfr[j] = *(const short8*)(Bp + (size_t)j * 16 * sB + k0);
#pragma unroll
    for (int i = 0; i < MR; ++i)
#pragma unroll
      for (int j = 0; j < NR; ++j)
        acc[i][j] = __builtin_amdgcn_mfma_f32_16x16x32_bf16(af[i], bfr[j], acc[i][j], 0, 0, 0);
  }
}

// ---------------- qkv GEMM: D[token][ch768] -> region-scatter fp32 q/k/v ----------------
__global__ __launch_bounds__(256) void k_gqkv(const u16* __restrict__ spkT, const u16* __restrict__ wT,
                                              const float* __restrict__ bias,
                                              float* __restrict__ qr, float* __restrict__ kr,
                                              float* __restrict__ vr) {
  f32x4 acc[4][4] = {};
  int n0 = blockIdx.x * 128, m0 = blockIdx.y * 128;
  mfma_core<4, 4, 2>(spkT + (size_t)m0 * 256, 256, wT + (size_t)n0 * 256, 256, 256, acc);
  int lane = threadIdx.x & 63, w = threadIdx.x >> 6;
  int wr = w >> 1, wc = w & 1;
#pragma unroll
  for (int i = 0; i < 4; ++i) {
#pragma unroll
    for (int reg = 0; reg < 4; ++reg) {
      int token = m0 + wr * 64 + i * 16 + (lane >> 4) * 4 + reg;
      int l = token & (LL - 1), nb = token >> 13;
      int lt = l >> 10, lh = (l >> 5) & 31, lw = l & 31;
      int r = ((lt >> 2) * 4 + (lh >> 3)) * 4 + (lw >> 3);
      int p = ((lt & 3) * 8 + (lh & 7)) * 8 + (lw & 7);
      size_t base = ((size_t)(nb * RR + r) * PPP + p) * CC;
#pragma unroll
      for (int j = 0; j < 4; ++j) {
        int ch = n0 + wc * 64 + j * 16 + (lane & 15);
        float v = acc[i][j][reg] + bias[ch];
        int which = ch >> 8, c = ch & 255;
        float* dst = (which == 0) ? qr : ((which == 1) ? kr : vr);
        dst[base + c] = v;
      }
    }
  }
}

// ---------------- FFN1 GEMM: D[token][j1024] -> GELU -> hbuf bf16 ----------------
__global__ __launch_bounds__(256) void k_gffn1(const u16* __restrict__ sT, const u16* __restrict__ wT,
                                               const float* __restrict__ bias, u16* __restrict__ hbuf) {
  f32x4 acc[4][4] = {};
  int n0 = blockIdx.x * 128, m0 = blockIdx.y * 128;
  mfma_core<4, 4, 2>(sT + (size_t)m0 * 256, 256, wT + (size_t)n0 * 256, 256, 256, acc);
  int lane = threadIdx.x & 63, w = threadIdx.x >> 6;
  int wr = w >> 1, wc = w & 1;
#pragma unroll
  for (int i = 0; i < 4; ++i) {
#pragma unroll
    for (int reg = 0; reg < 4; ++reg) {
      int token = m0 + wr * 64 + i * 16 + (lane >> 4) * 4 + reg;
#pragma unroll
      for (int j = 0; j < 4; ++j) {
        int ch = n0 + wc * 64 + j * 16 + (lane & 15);
        float z = acc[i][j][reg] + bias[ch];
        float gel = 0.5f * z * (1.f + erff(z * 0.70710678118654752f));
        hbuf[(size_t)token * 1024 + ch] = f2bf(gel);
      }
    }
  }
}

// ---------------- FFN2 GEMM (output-transposed): out[t][c][l] += (W2^T h + b2)*sc ----------------
__global__ __launch_bounds__(128) void k_gffn2(const u16* __restrict__ w2T, const u16* __restrict__ hb,
                                               const float* __restrict__ bias, const float* __restrict__ scale,
                                               float* __restrict__ out) {
  f32x4 acc[2][4] = {};
  int n0 = blockIdx.x * 128, m0 = blockIdx.y * 32;
  mfma_core<2, 4, 2>(w2T + (size_t)m0 * 1024, 1024, hb + (size_t)n0 * 1024, 1024, 1024, acc);
  int lane = threadIdx.x & 63, wc = threadIdx.x >> 6;
  float sc = scale[0];
#pragma unroll
  for (int i = 0; i < 2; ++i) {
#pragma unroll
    for (int reg = 0; reg < 4; ++reg) {
      int ch = m0 + i * 16 + (lane >> 4) * 4 + reg;
      float bb = bias[ch];
#pragma unroll
      for (int j = 0; j < 4; ++j) {
        int token = n0 + wc * 64 + j * 16 + (lane & 15);
        int t = token >> 13, l = token & (LL - 1);
        size_t oi = ((size_t)t * CC + ch) * LL + l;
        out[oi] += (acc[i][j][reg] + bb) * sc;
      }
    }
  }
}

// ---------------- Wo GEMM (output-transposed): out[t][c][l] = x + (Wo^T a + bo)*sc ----------------
__global__ __launch_bounds__(128) void k_gwo(const u16* __restrict__ woT, const u16* __restrict__ atok,
                                             const float* __restrict__ bias, const float* __restrict__ xin,
                                             const float* __restrict__ scale, float* __restrict__ out) {
  f32x4 acc[2][4] = {};
  int n0 = blockIdx.x * 128, m0 = blockIdx.y * 32;
  mfma_core<2, 4, 2>(woT + (size_t)m0 * 256, 256, atok + (size_t)n0 * 256, 256, 256, acc);
  int lane = threadIdx.x & 63, wc = threadIdx.x >> 6;
  float sc = scale[0];
#pragma unroll
  for (int i = 0; i < 2; ++i) {
#pragma unroll
    for (int reg = 0; reg < 4; ++reg) {
      int ch = m0 + i * 16 + (lane >> 4) * 4 + reg;
      float bb = bias[ch];
#pragma unroll
      for (int j = 0; j < 4; ++j) {
        int token = n0 + wc * 64 + j * 16 + (lane & 15);
        int t = token >> 13, l = token & (LL - 1);
        size_t oi = ((size_t)t * CC + ch) * LL + l;
        out[oi] = xin[oi] + (acc[i][j][reg] + bb) * sc;
      }
    }
  }
}

// ---------------- region means ----------------
__global__ __launch_bounds__(256) void k_means(const float* __restrict__ qr,
                                               const float* __restrict__ kr,
                                               float* __restrict__ qm,
                                               float* __restrict__ km) {
  int nr = blockIdx.x;
  int c = threadIdx.x;
  size_t base = (size_t)nr * PPP * CC + c;
  float sq = 0.f, sk = 0.f;
  for (int p = 0; p < PPP; ++p) {
    sq += qr[base + (size_t)p * CC];
    sk += kr[base + (size_t)p * CC];
  }
  qm[nr * CC + c] = sq * (1.f / PPP);
  km[nr * CC + c] = sk * (1.f / PPP);
}

// ---------------- routing top-4 ----------------
__global__ __launch_bounds__(64) void k_route(const float* __restrict__ qm,
                                              const float* __restrict__ km,
                                              int* __restrict__ idx) {
  int nr = blockIdx.x;
  int n = nr >> 5;
  int tid = threadIdx.x;
  __shared__ float ar[32];
  if (tid < 32) {
    const float* qrow = qm + nr * CC;
    const float* krow = km + (n * RR + tid) * CC;
    float s = 0.f;
    for (int c = 0; c < CC; ++c) s += qrow[c] * krow[c];
    ar[tid] = s;
  }
  __syncthreads();
  if (tid == 0) {
    for (int t = 0; t < NTOP; ++t) {
      float best = -1e30f; int bi = 0;
      for (int s = 0; s < 32; ++s)
        if (ar[s] > best) { best = ar[s]; bi = s; }
      ar[bi] = -1e30f;
      idx[nr * NTOP + t] = bi;
    }
  }
}

// ---------------- attention, split-2 over topk regions; unnormalized partials ----------------
__global__ __launch_bounds__(128) void k_attn2(const float* __restrict__ qr,
                                               const float* __restrict__ kr,
                                               const float* __restrict__ vr,
                                               const int* __restrict__ idx,
                                               float* __restrict__ op0,
                                               float* __restrict__ op1,
                                               float* __restrict__ lpart) {
  int h = blockIdx.x, r = blockIdx.y, nz = blockIdx.z;
  int n = nz >> 1, s = nz & 1;
  int tid = threadIdx.x;
  __shared__ float4 ks4[1024];
  __shared__ float4 vs4[1024];
  const float qs = 0.17677669529663687f;
  float4 q0[8], q1[8], o0[8], o1[8];
  size_t qbase = ((size_t)(n * RR + r) * PPP) * CC + h * 32;
#pragma unroll
  for (int d = 0; d < 8; ++d) {
    float4 t0 = *(const float4*)&qr[qbase + (size_t)tid * CC + d * 4];
    float4 t1 = *(const float4*)&qr[qbase + (size_t)(tid + 128) * CC + d * 4];
    q0[d] = make_float4(t0.x * qs, t0.y * qs, t0.z * qs, t0.w * qs);
    q1[d] = make_float4(t1.x * qs, t1.y * qs, t1.z * qs, t1.w * qs);
    o0[d] = make_float4(0.f, 0.f, 0.f, 0.f);
    o1[d] = make_float4(0.f, 0.f, 0.f, 0.f);
  }
  float l0 = 0.f, l1 = 0.f;
  for (int kii = 0; kii < 2; ++kii) {
    int ki = s * 2 + kii;
    int reg = idx[(n * RR + r) * NTOP + ki];
    size_t kb = ((size_t)(n * RR + reg) * PPP) * CC + h * 32;
    for (int half = 0; half < 2; ++half) {
      __syncthreads();
#pragma unroll
      for (int i = 0; i < 8; ++i) {
        int lin = i * 128 + tid;
        int row = lin >> 3, d4 = lin & 7;
        size_t ga = kb + (size_t)(half * 128 + row) * CC + d4 * 4;
        ks4[lin] = *(const float4*)&kr[ga];
        vs4[lin] = *(const float4*)&vr[ga];
      }
      __syncthreads();
      for (int kk = 0; kk < 128; ++kk) {
        const float4* krow = &ks4[kk * 8];
        float d0[8], d1[8];
#pragma unroll
        for (int d = 0; d < 8; ++d) {
          float4 kf = krow[d];
          d0[d] = q0[d].x * kf.x + q0[d].y * kf.y + q0[d].z * kf.z + q0[d].w * kf.w;
          d1[d] = q1[d].x * kf.x + q1[d].y * kf.y + q1[d].z * kf.z + q1[d].w * kf.w;
        }
        float s0 = ((d0[0] + d0[1]) + (d0[2] + d0[3])) + ((d0[4] + d0[5]) + (d0[6] + d0[7]));
        float s1 = ((d1[0] + d1[1]) + (d1[2] + d1[3])) + ((d1[4] + d1[5]) + (d1[6] + d1[7]));
        float p0 = __expf(s0), p1 = __expf(s1);
        l0 += p0; l1 += p1;
        const float4* vrow = &vs4[kk * 8];
#pragma unroll
        for (int d = 0; d < 8; ++d) {
          float4 vf = vrow[d];
          o0[d].x = fmaf(p0, vf.x, o0[d].x);
          o0[d].y = fmaf(p0, vf.y, o0[d].y);
          o0[d].z = fmaf(p0, vf.z, o0[d].z);
          o0[d].w = fmaf(p0, vf.w, o0[d].w);
          o1[d].x = fmaf(p1, vf.x, o1[d].x);
          o1[d].y = fmaf(p1, vf.y, o1[d].y);
          o1[d].z = fmaf(p1, vf.z, o1[d].z);
          o1[d].w = fmaf(p1, vf.w, o1[d].w);
        }
      }
    }
  }
  float* op = s ? op1 : op0;
  size_t ob0 = ((size_t)(n * RR + r) * PPP + tid) * CC + h * 32;
  size_t ob1 = ((size_t)(n * RR + r) * PPP + tid + 128) * CC + h * 32;
#pragma unroll
  for (int d = 0; d < 8; ++d) {
    *(float4*)&op[ob0 + d * 4] = o0[d];
    *(float4*)&op[ob1 + d * 4] = o1[d];
  }
  int lb = (((n * RR + r) * 2 + s) * 8 + h) * PPP;
  lpart[lb + tid] = l0;
  lpart[lb + tid + 128] = l1;
}

// ---------------- combine partials: op0 = (op0+op1)/(l0+l1) ----------------
__global__ __launch_bounds__(256) void k_comb(float* __restrict__ op0,
                                              const float* __restrict__ op1,
                                              const float* __restrict__ lpart) {
  int gid = blockIdx.x * 256 + threadIdx.x;   // over 1,048,576 float4 groups
  int c4 = gid & 63;
  int p = (gid >> 6) & 255;
  int nr = gid >> 14;
  int h = c4 >> 3;
  float l0 = lpart[((nr * 2 + 0) * 8 + h) * PPP + p];
  float l1 = lpart[((nr * 2 + 1) * 8 + h) * PPP + p];
  float inv = 1.f / (l0 + l1);
  size_t o = ((size_t)(nr * PPP + p) * CC) + c4 * 4;
  float4 a = *(const float4*)&op0[o];
  float4 b = *(const float4*)&op1[o];
  *(float4*)&op0[o] = make_float4((a.x + b.x) * inv, (a.y + b.y) * inv,
                                  (a.z + b.z) * inv, (a.w + b.w) * inv);
}

// ---------------- from_reg + LEPE -> token-major bf16 ----------------
__global__ __launch_bounds__(256) void k_lepe(const float* __restrict__ oreg,
                                              const float* __restrict__ vr,
                                              const float* __restrict__ w,
                                              u16* __restrict__ otok) {
  int blk = blockIdx.x;                 // n*256 + lt*32 + lh
  int lh = blk & 31, lt = (blk >> 5) & 7, n = blk >> 8;
  int c = threadIdx.x;
  __shared__ float wl[27 * 256];
  for (int i = threadIdx.x; i < 27 * 256; i += 256) {
    int cc = i / 27, tp = i % 27;
    wl[tp * 256 + cc] = w[i];
  }
  __syncthreads();
  for (int lw = 0; lw < 32; ++lw) {
    int r = ((lt >> 2) * 4 + (lh >> 3)) * 4 + (lw >> 3);
    int p = ((lt & 3) * 8 + (lh & 7)) * 8 + (lw & 7);
    float acc = oreg[((size_t)(n * RR + r) * PPP + p) * CC + c];
    float lep = 0.f;
    for (int dz = -1; dz <= 1; ++dz) {
      int z = lt + dz;
      if (z < 0 || z >= 8) continue;
      for (int dy = -1; dy <= 1; ++dy) {
        int y = lh + dy;
        if (y < 0 || y >= 32) continue;
        for (int dx = -1; dx <= 1; ++dx) {
          int xx = lw + dx;
          if (xx < 0 || xx >= 32) continue;
          int r2 = ((z >> 2) * 4 + (y >> 3)) * 4 + (xx >> 3);
          int p2 = ((z & 3) * 8 + (y & 7)) * 8 + (xx & 7);
          int tap = ((dz + 1) * 3 + (dy + 1)) * 3 + (dx + 1);
          lep = fmaf(wl[tap * 256 + c], vr[((size_t)(n * RR + r2) * PPP + p2) * CC + c], lep);
        }
      }
    }
    int l = (lt * 32 + lh) * 32 + lw;
    otok[((size_t)n * LL + l) * CC + c] = f2bf(acc + lep);
  }
}

extern "C" void kernel_launch(void* const* d_in, const int* in_sizes, int n_in,
                              void* d_out, int out_size, void* d_ws, size_t ws_size,
                              hipStream_t stream) {
  const float* x      = (const float*)d_in[0];
  const float* bn1_g  = (const float*)d_in[1];
  const float* bn1_b  = (const float*)d_in[2];
  const float* wqkv   = (const float*)d_in[3];
  const float* bqkv   = (const float*)d_in[4];
  const float* lepe_w = (const float*)d_in[5];
  const float* wo_w   = (const float*)d_in[6];
  const float* bo     = (const float*)d_in[7];
  const float* bn2_g  = (const float*)d_in[8];
  const float* bn2_b  = (const float*)d_in[9];
  const float* ffn_w1 = (const float*)d_in[10];
  const float* ffn_b1 = (const float*)d_in[11];
  const float* ffn_w2 = (const float*)d_in[12];
  const float* ffn_b2 = (const float*)d_in[13];
  const float* scale  = (const float*)d_in[14];
  float* out = (float*)d_out;

  float* ws    = (float*)d_ws;
  float* spk   = ws;                           // 4,194,304 fl (also opart1, s2)
  u16*   actT  = (u16*)(ws + 4194304);         // 4,194,304 u16: spkT / otok / s2T
  float* qr    = ws + 6291456;
  float* kr    = ws + 10485760;
  float* vr    = ws + 14680064;
  float* op0   = ws + 18874368;                // oreg
  u16*   hbuf  = (u16*)(ws + 6291456);         // 16,777,216 u16 over qr+kr (dead then)
  float* lpart = ws + 23068672;                // 262,144
  u16*   wqkvT = (u16*)(ws + 23330816);        // 196,608 u16
  u16*   w1T   = (u16*)(ws + 23429120);        // 262,144 u16
  u16*   w2T   = (u16*)(ws + 23560192);        // 262,144 u16
  u16*   woT   = (u16*)(ws + 23691264);        // 65,536 u16
  float* sm    = ws + 23724032;
  float* mean1 = sm;
  float* istd1 = sm + 256;
  float* mean2 = sm + 512;
  float* istd2 = sm + 768;
  float* qm    = sm + 1024;
  float* km    = sm + 1024 + 16384;
  int*   idxb  = (int*)(sm + 1024 + 32768);

  // weight transposes (bf16, [n][k])
  k_tr<<<dim3(24, 8, 1), 256, 0, stream>>>(wqkv, wqkvT, 256, 768, 0, 0);
  k_tr<<<dim3(32, 8, 1), 256, 0, stream>>>(ffn_w1, w1T, 256, 1024, 0, 0);
  k_tr<<<dim3(8, 32, 1), 256, 0, stream>>>(ffn_w2, w2T, 1024, 256, 0, 0);
  k_tr<<<dim3(8, 8, 1), 256, 0, stream>>>(wo_w, woT, 256, 256, 0, 0);

  // ---- attention branch ----
  k_bnstats<<<256, 256, 0, stream>>>(x, mean1, istd1);
  k_lif<<<8192, 256, 0, stream>>>(x, mean1, istd1, bn1_g, bn1_b, spk);
  k_tr<<<dim3(256, 8, 2), 256, 0, stream>>>(spk, actT, 256, 8192, 2097152L, 2097152L);
  k_gqkv<<<dim3(6, 128), 256, 0, stream>>>(actT, wqkvT, bqkv, qr, kr, vr);
  k_means<<<64, 256, 0, stream>>>(qr, kr, qm, km);
  k_route<<<64, 64, 0, stream>>>(qm, km, idxb);
  k_attn2<<<dim3(8, RR, 4), 128, 0, stream>>>(qr, kr, vr, idxb, op0, spk, lpart);
  k_comb<<<4096, 256, 0, stream>>>(op0, spk, lpart);
  k_lepe<<<512, 256, 0, stream>>>(op0, vr, lepe_w, actT);
  k_gwo<<<dim3(128, 8), 128, 0, stream>>>(woT, actT, bo, x, scale, out);

  // ---- FFN branch ----
  k_bnstats<<<256, 256, 0, stream>>>(out, mean2, istd2);
  k_lif<<<8192, 256, 0, stream>>>(out, mean2, istd2, bn2_g, bn2_b, spk);
  k_tr<<<dim3(256, 8, 2), 256, 0, stream>>>(spk, actT, 256, 8192, 2097152L, 2097152L);
  k_gffn1<<<dim3(8, 128), 256, 0, stream>>>(actT, w1T, ffn_b1, hbuf);
  k_gffn2<<<dim3(128, 8), 128, 0, stream>>>(w2T, hbuf, ffn_b2, scale, out);
}

// Round 3
// 426.415 us; speedup vs baseline: 2.2012x; 1.4331x over previous
//
#include <hip/hip_runtime.h>
#include <math.h>

#define CC 256
#define LL 8192
#define RR 32
#define PPP 256
#define NTOP 4

typedef unsigned short u16;
typedef __attribute__((ext_vector_type(8))) short short8;
typedef __attribute__((ext_vector_type(4))) float f32x4;
typedef __attribute__((ext_vector_type(4))) unsigned short u16x4;

__device__ inline u16 f2bf(float f) {
  unsigned int b = __float_as_uint(f);
  unsigned int r = (b + 0x7FFFu + ((b >> 16) & 1u)) >> 16;
  return (u16)r;
}
__device__ inline float bf2f(u16 x) { return __uint_as_float(((unsigned int)x) << 16); }

// ---------------- BN stats ----------------
__global__ __launch_bounds__(256) void k_bnstats(const float* __restrict__ x,
                                                 float* __restrict__ mean,
                                                 float* __restrict__ istd) {
  int c = blockIdx.x, tid = threadIdx.x;
  float s = 0.f, sq = 0.f;
  for (int i = tid; i < 2 * LL; i += 256) {
    int t = i >> 13, l = i & (LL - 1);
    float v = x[(t * CC + c) * LL + l];
    s += v; sq += v * v;
  }
  __shared__ float rs[256], rq[256];
  rs[tid] = s; rq[tid] = sq;
  __syncthreads();
  for (int off = 128; off > 0; off >>= 1) {
    if (tid < off) { rs[tid] += rs[tid + off]; rq[tid] += rq[tid + off]; }
    __syncthreads();
  }
  if (tid == 0) {
    float m = rs[0] * (1.f / (2 * LL));
    float var = rq[0] * (1.f / (2 * LL)) - m * m;
    mean[c] = m;
    istd[c] = rsqrtf(var + 1e-5f);
  }
}

// ---------------- BN + 2-step LIF -> spikes [t][c][l] fp32 ----------------
__global__ __launch_bounds__(256) void k_lif(const float* __restrict__ xin,
                                             const float* __restrict__ mean,
                                             const float* __restrict__ istd,
                                             const float* __restrict__ g,
                                             const float* __restrict__ b,
                                             float* __restrict__ spk) {
  int i = blockIdx.x * 256 + threadIdx.x;
  int c = i >> 13;
  float m = mean[c], is = istd[c], gg = g[c], bb = b[c];
  float x0 = xin[i];
  float x1 = xin[CC * LL + i];
  float y0 = gg * (x0 - m) * is + bb;
  float y1 = gg * (x1 - m) * is + bb;
  float v = 0.f;
  v += (y0 - v) * 0.5f;
  float s0 = (v >= 1.f) ? 1.f : 0.f;
  v -= s0;
  v += (y1 - v) * 0.5f;
  float s1 = (v >= 1.f) ? 1.f : 0.f;
  spk[i] = s0;
  spk[CC * LL + i] = s1;
}

// ---------------- fp32 [R][C] -> bf16 [C][R] transpose (batched via z) ----------------
__global__ __launch_bounds__(256) void k_tr(const float* __restrict__ in, u16* __restrict__ out,
                                            int R, int C, long ibs, long obs) {
  __shared__ float t[32][33];
  const float* ib = in + (size_t)blockIdx.z * ibs;
  u16* ob = out + (size_t)blockIdx.z * obs;
  int c0 = blockIdx.x * 32, r0 = blockIdx.y * 32;
  int tx = threadIdx.x & 31, ty = threadIdx.x >> 5;
  for (int i = 0; i < 32; i += 8)
    t[ty + i][tx] = ib[(size_t)(r0 + ty + i) * C + c0 + tx];
  __syncthreads();
  for (int i = 0; i < 32; i += 8)
    ob[(size_t)(c0 + ty + i) * R + r0 + tx] = f2bf(t[tx][ty + i]);
}

// ---------------- MFMA core: D[m][n] += A[m][k]*B[n][k]^T, K-contiguous bf16 ----------------
template<int MR, int NR, int WCN>
__device__ inline void mfma_core(const u16* __restrict__ A0, int sA,
                                 const u16* __restrict__ B0, int sB,
                                 int K, f32x4 acc[MR][NR]) {
  int lane = threadIdx.x & 63;
  int w = threadIdx.x >> 6;
  int wr = w / WCN, wc = w % WCN;
  int rr = lane & 15;
  int g8 = (lane >> 4) * 8;
  const u16* Ap = A0 + (size_t)(wr * MR * 16 + rr) * sA + g8;
  const u16* Bp = B0 + (size_t)(wc * NR * 16 + rr) * sB + g8;
  for (int k0 = 0; k0 < K; k0 += 32) {
    short8 af[MR], bfr[NR];
#pragma unroll
    for (int i = 0; i < MR; ++i)
      af[i] = *(const short8*)(Ap + (size_t)i * 16 * sA + k0);
#pragma unroll
    for (int j = 0; j < NR; ++j)
      bfr[j] = *(const short8*)(Bp + (size_t)j * 16 * sB + k0);
#pragma unroll
    for (int i = 0; i < MR; ++i)
#pragma unroll
      for (int j = 0; j < NR; ++j)
        acc[i][j] = __builtin_amdgcn_mfma_f32_16x16x32_bf16(af[i], bfr[j], acc[i][j], 0, 0, 0);
  }
}

// ---------------- qkv GEMM -> bf16 per-head q/k, transposed v, fp32 vr ----------------
__global__ __launch_bounds__(256) void k_gqkv(const u16* __restrict__ spkT, const u16* __restrict__ wT,
                                              const float* __restrict__ bias,
                                              u16* __restrict__ qh, u16* __restrict__ kh,
                                              u16* __restrict__ vt, float* __restrict__ vr) {
  f32x4 acc[4][4] = {};
  int n0 = blockIdx.x * 128, m0 = blockIdx.y * 128;
  mfma_core<4, 4, 2>(spkT + (size_t)m0 * 256, 256, wT + (size_t)n0 * 256, 256, 256, acc);
  int lane = threadIdx.x & 63, w = threadIdx.x >> 6;
  int wr = w >> 1, wc = w & 1;
  int u = lane & 15;
#pragma unroll
  for (int i = 0; i < 4; ++i) {
#pragma unroll
    for (int reg = 0; reg < 4; ++reg) {
      int token = m0 + wr * 64 + i * 16 + (lane >> 4) * 4 + reg;
      int l = token & (LL - 1), nb = token >> 13;
      int lt = l >> 10, lh = (l >> 5) & 31, lw = l & 31;
      int r = ((lt >> 2) * 4 + (lh >> 3)) * 4 + (lw >> 3);
      int p = ((lt & 3) * 8 + (lh & 7)) * 8 + (lw & 7);
      int nr = nb * RR + r;
#pragma unroll
      for (int j = 0; j < 4; ++j) {
        int ch = n0 + wc * 64 + j * 16 + u;
        float val = acc[i][j][reg] + bias[ch];
        int which = ch >> 8, c = ch & 255;
        int hh = c >> 5, dh = c & 31;
        size_t hb = ((size_t)nr * 8 + hh) * 8192;
        if (which == 0) {
          qh[hb + p * 32 + dh] = f2bf(val);
        } else if (which == 1) {
          kh[hb + p * 32 + dh] = f2bf(val);
        } else {
          vt[hb + dh * 256 + p] = f2bf(val);
          vr[((size_t)nr * 256 + p) * 256 + c] = val;
        }
      }
    }
  }
}

// ---------------- region means from bf16 heads ----------------
__global__ __launch_bounds__(256) void k_means(const u16* __restrict__ qh, const u16* __restrict__ kh,
                                               float* __restrict__ qm, float* __restrict__ km) {
  int nr = blockIdx.x, c = threadIdx.x;
  int hh = c >> 5, dh = c & 31;
  size_t base = ((size_t)nr * 8 + hh) * 8192 + dh;
  float sq = 0.f, sk = 0.f;
  for (int p = 0; p < 256; ++p) {
    sq += bf2f(qh[base + p * 32]);
    sk += bf2f(kh[base + p * 32]);
  }
  qm[nr * 256 + c] = sq * (1.f / 256);
  km[nr * 256 + c] = sk * (1.f / 256);
}

// ---------------- routing top-4 ----------------
__global__ __launch_bounds__(64) void k_route(const float* __restrict__ qm,
                                              const float* __restrict__ km,
                                              int* __restrict__ idx) {
  int nr = blockIdx.x;
  int n = nr >> 5;
  int tid = threadIdx.x;
  __shared__ float ar[32];
  if (tid < 32) {
    const float* qrow = qm + nr * CC;
    const float* krow = km + (n * RR + tid) * CC;
    float s = 0.f;
    for (int c = 0; c < CC; ++c) s += qrow[c] * krow[c];
    ar[tid] = s;
  }
  __syncthreads();
  if (tid == 0) {
    for (int t = 0; t < NTOP; ++t) {
      float best = -1e30f; int bi = 0;
      for (int s = 0; s < 32; ++s)
        if (ar[s] > best) { best = ar[s]; bi = s; }
      ar[bi] = -1e30f;
      idx[nr * NTOP + t] = bi;
    }
  }
}

// ---------------- MFMA flash attention: block (h, r, n), 4 waves x 64 q-rows ----------------
__global__ __launch_bounds__(256) void k_attn_mfma(const u16* __restrict__ qh,
                                                   const u16* __restrict__ kh,
                                                   const u16* __restrict__ vt,
                                                   const int* __restrict__ idx,
                                                   float* __restrict__ oreg) {
  int h = blockIdx.x, r = blockIdx.y, n = blockIdx.z;
  int nr = n * RR + r;
  int lane = threadIdx.x & 63;
  int w = threadIdx.x >> 6;
  int u = lane & 15, g = lane >> 4;
  const float qs = 0.17677669529663687f;  // 32^-0.5
  __shared__ u16 pl[4 * 2560];            // per-wave 64 q-rows x (32+8 pad) keys bf16
  u16* plw = &pl[w * 2560];

  // Q fragments: 64 rows for this wave, K-contig direct loads
  const u16* qb = qh + ((size_t)nr * 8 + h) * 8192;
  int q0 = w * 64;
  short8 qf[4];
#pragma unroll
  for (int f = 0; f < 4; ++f)
    qf[f] = *(const short8*)(qb + (size_t)(q0 + f * 16 + u) * 32 + g * 8);

  f32x4 accO[2][4] = {};
  float lsum[4] = {0.f, 0.f, 0.f, 0.f};
  const int* idxp = &idx[nr * NTOP];

  for (int kt = 0; kt < 32; ++kt) {
    int reg = idxp[kt >> 3];
    int pb = (kt & 7) * 32;
    size_t rb = ((size_t)(n * RR + reg) * 8 + h) * 8192;
    short8 kf0 = *(const short8*)(kh + rb + (size_t)(pb + u) * 32 + g * 8);
    short8 kf1 = *(const short8*)(kh + rb + (size_t)(pb + 16 + u) * 32 + g * 8);
    short8 vf0 = *(const short8*)(vt + rb + (size_t)(u) * 256 + pb + g * 8);
    short8 vf1 = *(const short8*)(vt + rb + (size_t)(16 + u) * 256 + pb + g * 8);

    // S^T = K x Q : D[key][q]
    f32x4 s[2][4];
#pragma unroll
    for (int nf = 0; nf < 4; ++nf) {
      s[0][nf] = __builtin_amdgcn_mfma_f32_16x16x32_bf16(kf0, qf[nf], (f32x4){0.f, 0.f, 0.f, 0.f}, 0, 0, 0);
      s[1][nf] = __builtin_amdgcn_mfma_f32_16x16x32_bf16(kf1, qf[nf], (f32x4){0.f, 0.f, 0.f, 0.f}, 0, 0, 0);
    }
    // exp -> bf16 pack into LDS (P[q][key]); lsum from the ROUNDED weights
#pragma unroll
    for (int nf = 0; nf < 4; ++nf) {
#pragma unroll
      for (int mf = 0; mf < 2; ++mf) {
        u16 b0 = f2bf(__expf(s[mf][nf][0] * qs));
        u16 b1 = f2bf(__expf(s[mf][nf][1] * qs));
        u16 b2 = f2bf(__expf(s[mf][nf][2] * qs));
        u16 b3 = f2bf(__expf(s[mf][nf][3] * qs));
        lsum[nf] += (bf2f(b0) + bf2f(b1)) + (bf2f(b2) + bf2f(b3));
        *(u16x4*)&plw[(nf * 16 + u) * 40 + mf * 16 + g * 4] = (u16x4){b0, b1, b2, b3};
      }
    }
    // PV: D[dh][q] += Vt x P
#pragma unroll
    for (int nf = 0; nf < 4; ++nf) {
      short8 pf = *(const short8*)&plw[(nf * 16 + u) * 40 + g * 8];
      accO[0][nf] = __builtin_amdgcn_mfma_f32_16x16x32_bf16(vf0, pf, accO[0][nf], 0, 0, 0);
      accO[1][nf] = __builtin_amdgcn_mfma_f32_16x16x32_bf16(vf1, pf, accO[1][nf], 0, 0, 0);
    }
  }

#pragma unroll
  for (int nf = 0; nf < 4; ++nf) {
    lsum[nf] += __shfl_xor(lsum[nf], 16);
    lsum[nf] += __shfl_xor(lsum[nf], 32);
    float inv = 1.f / lsum[nf];
    int q = q0 + nf * 16 + u;
    float* ob = &oreg[((size_t)nr * 256 + q) * 256 + h * 32];
#pragma unroll
    for (int mf = 0; mf < 2; ++mf) {
      f32x4 o = accO[mf][nf];
      *(float4*)&ob[mf * 16 + g * 4] =
          make_float4(o[0] * inv, o[1] * inv, o[2] * inv, o[3] * inv);
    }
  }
}

// ---------------- from_reg + LEPE -> token-major bf16 ----------------
__global__ __launch_bounds__(256) void k_lepe(const float* __restrict__ oreg,
                                              const float* __restrict__ vr,
                                              const float* __restrict__ w,
                                              u16* __restrict__ otok) {
  int blk = blockIdx.x;
  int lh = blk & 31, lt = (blk >> 5) & 7, n = blk >> 8;
  int c = threadIdx.x;
  __shared__ float wl[27 * 256];
  for (int i = threadIdx.x; i < 27 * 256; i += 256) {
    int cc = i / 27, tp = i % 27;
    wl[tp * 256 + cc] = w[i];
  }
  __syncthreads();
  for (int lw = 0; lw < 32; ++lw) {
    int r = ((lt >> 2) * 4 + (lh >> 3)) * 4 + (lw >> 3);
    int p = ((lt & 3) * 8 + (lh & 7)) * 8 + (lw & 7);
    float acc = oreg[((size_t)(n * RR + r) * PPP + p) * CC + c];
    float lep = 0.f;
    for (int dz = -1; dz <= 1; ++dz) {
      int z = lt + dz;
      if (z < 0 || z >= 8) continue;
      for (int dy = -1; dy <= 1; ++dy) {
        int y = lh + dy;
        if (y < 0 || y >= 32) continue;
        for (int dx = -1; dx <= 1; ++dx) {
          int xx = lw + dx;
          if (xx < 0 || xx >= 32) continue;
          int r2 = ((z >> 2) * 4 + (y >> 3)) * 4 + (xx >> 3);
          int p2 = ((z & 3) * 8 + (y & 7)) * 8 + (xx & 7);
          int tap = ((dz + 1) * 3 + (dy + 1)) * 3 + (dx + 1);
          lep = fmaf(wl[tap * 256 + c], vr[((size_t)(n * RR + r2) * PPP + p2) * CC + c], lep);
        }
      }
    }
    int l = (lt * 32 + lh) * 32 + lw;
    otok[((size_t)n * LL + l) * CC + c] = f2bf(acc + lep);
  }
}

// ---------------- FFN1 GEMM -> GELU -> hbuf bf16 ----------------
__global__ __launch_bounds__(256) void k_gffn1(const u16* __restrict__ sT, const u16* __restrict__ wT,
                                               const float* __restrict__ bias, u16* __restrict__ hbuf) {
  f32x4 acc[4][4] = {};
  int n0 = blockIdx.x * 128, m0 = blockIdx.y * 128;
  mfma_core<4, 4, 2>(sT + (size_t)m0 * 256, 256, wT + (size_t)n0 * 256, 256, 256, acc);
  int lane = threadIdx.x & 63, w = threadIdx.x >> 6;
  int wr = w >> 1, wc = w & 1;
#pragma unroll
  for (int i = 0; i < 4; ++i) {
#pragma unroll
    for (int reg = 0; reg < 4; ++reg) {
      int token = m0 + wr * 64 + i * 16 + (lane >> 4) * 4 + reg;
#pragma unroll
      for (int j = 0; j < 4; ++j) {
        int ch = n0 + wc * 64 + j * 16 + (lane & 15);
        float z = acc[i][j][reg] + bias[ch];
        float gel = 0.5f * z * (1.f + erff(z * 0.70710678118654752f));
        hbuf[(size_t)token * 1024 + ch] = f2bf(gel);
      }
    }
  }
}

// ---------------- FFN2 GEMM (output-transposed): out[t][c][l] += (W2^T h + b2)*sc ----------------
__global__ __launch_bounds__(128) void k_gffn2(const u16* __restrict__ w2T, const u16* __restrict__ hb,
                                               const float* __restrict__ bias, const float* __restrict__ scale,
                                               float* __restrict__ out) {
  f32x4 acc[2][4] = {};
  int n0 = blockIdx.x * 128, m0 = blockIdx.y * 32;
  mfma_core<2, 4, 2>(w2T + (size_t)m0 * 1024, 1024, hb + (size_t)n0 * 1024, 1024, 1024, acc);
  int lane = threadIdx.x & 63, wc = threadIdx.x >> 6;
  float sc = scale[0];
#pragma unroll
  for (int i = 0; i < 2; ++i) {
#pragma unroll
    for (int reg = 0; reg < 4; ++reg) {
      int ch = m0 + i * 16 + (lane >> 4) * 4 + reg;
      float bb = bias[ch];
#pragma unroll
      for (int j = 0; j < 4; ++j) {
        int token = n0 + wc * 64 + j * 16 + (lane & 15);
        int t = token >> 13, l = token & (LL - 1);
        size_t oi = ((size_t)t * CC + ch) * LL + l;
        out[oi] += (acc[i][j][reg] + bb) * sc;
      }
    }
  }
}

// ---------------- Wo GEMM (output-transposed): out[t][c][l] = x + (Wo^T a + bo)*sc ----------------
__global__ __launch_bounds__(128) void k_gwo(const u16* __restrict__ woT, const u16* __restrict__ atok,
                                             const float* __restrict__ bias, const float* __restrict__ xin,
                                             const float* __restrict__ scale, float* __restrict__ out) {
  f32x4 acc[2][4] = {};
  int n0 = blockIdx.x * 128, m0 = blockIdx.y * 32;
  mfma_core<2, 4, 2>(woT + (size_t)m0 * 256, 256, atok + (size_t)n0 * 256, 256, 256, acc);
  int lane = threadIdx.x & 63, wc = threadIdx.x >> 6;
  float sc = scale[0];
#pragma unroll
  for (int i = 0; i < 2; ++i) {
#pragma unroll
    for (int reg = 0; reg < 4; ++reg) {
      int ch = m0 + i * 16 + (lane >> 4) * 4 + reg;
      float bb = bias[ch];
#pragma unroll
      for (int j = 0; j < 4; ++j) {
        int token = n0 + wc * 64 + j * 16 + (lane & 15);
        int t = token >> 13, l = token & (LL - 1);
        size_t oi = ((size_t)t * CC + ch) * LL + l;
        out[oi] = xin[oi] + (acc[i][j][reg] + bb) * sc;
      }
    }
  }
}

extern "C" void kernel_launch(void* const* d_in, const int* in_sizes, int n_in,
                              void* d_out, int out_size, void* d_ws, size_t ws_size,
                              hipStream_t stream) {
  const float* x      = (const float*)d_in[0];
  const float* bn1_g  = (const float*)d_in[1];
  const float* bn1_b  = (const float*)d_in[2];
  const float* wqkv   = (const float*)d_in[3];
  const float* bqkv   = (const float*)d_in[4];
  const float* lepe_w = (const float*)d_in[5];
  const float* wo_w   = (const float*)d_in[6];
  const float* bo     = (const float*)d_in[7];
  const float* bn2_g  = (const float*)d_in[8];
  const float* bn2_b  = (const float*)d_in[9];
  const float* ffn_w1 = (const float*)d_in[10];
  const float* ffn_b1 = (const float*)d_in[11];
  const float* ffn_w2 = (const float*)d_in[12];
  const float* ffn_b2 = (const float*)d_in[13];
  const float* scale  = (const float*)d_in[14];
  float* out = (float*)d_out;

  float* ws    = (float*)d_ws;
  float* spk   = ws;                           // [0, 4M) fl : spikes (branch 1 & 2)
  u16*   actT  = (u16*)(ws + 4194304);         // [4M, 6M) : spkT / otok / s2T (4M u16)
  u16*   qhead = (u16*)(ws + 6291456);         // 4M u16
  u16*   khead = (u16*)(ws + 8388608);         // 4M u16
  u16*   vthead= (u16*)(ws + 10485760);        // 4M u16
  float* vr    = ws + 12582912;                // 4M fl
  float* oreg  = ws + 16777216;                // 4M fl
  u16*   hbuf  = (u16*)(ws + 6291456);         // 16M u16, overlaps qhead..vr (dead in FFN)
  u16*   wqkvT = (u16*)(ws + 20971520);
  u16*   w1T   = (u16*)(ws + 21069824);
  u16*   w2T   = (u16*)(ws + 21200896);
  u16*   woT   = (u16*)(ws + 21331968);
  float* sm    = ws + 21364736;
  float* mean1 = sm;
  float* istd1 = sm + 256;
  float* mean2 = sm + 512;
  float* istd2 = sm + 768;
  float* qm    = sm + 1024;
  float* km    = sm + 1024 + 16384;
  int*   idxb  = (int*)(sm + 1024 + 32768);

  // weight transposes (bf16, [n][k])
  k_tr<<<dim3(24, 8, 1), 256, 0, stream>>>(wqkv, wqkvT, 256, 768, 0, 0);
  k_tr<<<dim3(32, 8, 1), 256, 0, stream>>>(ffn_w1, w1T, 256, 1024, 0, 0);
  k_tr<<<dim3(8, 32, 1), 256, 0, stream>>>(ffn_w2, w2T, 1024, 256, 0, 0);
  k_tr<<<dim3(8, 8, 1), 256, 0, stream>>>(wo_w, woT, 256, 256, 0, 0);

  // ---- attention branch ----
  k_bnstats<<<256, 256, 0, stream>>>(x, mean1, istd1);
  k_lif<<<8192, 256, 0, stream>>>(x, mean1, istd1, bn1_g, bn1_b, spk);
  k_tr<<<dim3(256, 8, 2), 256, 0, stream>>>(spk, actT, 256, 8192, 2097152L, 2097152L);
  k_gqkv<<<dim3(6, 128), 256, 0, stream>>>(actT, wqkvT, bqkv, qhead, khead, vthead, vr);
  k_means<<<64, 256, 0, stream>>>(qhead, khead, qm, km);
  k_route<<<64, 64, 0, stream>>>(qm, km, idxb);
  k_attn_mfma<<<dim3(8, RR, 2), 256, 0, stream>>>(qhead, khead, vthead, idxb, oreg);
  k_lepe<<<512, 256, 0, stream>>>(oreg, vr, lepe_w, actT);
  k_gwo<<<dim3(128, 8), 128, 0, stream>>>(woT, actT, bo, x, scale, out);

  // ---- FFN branch ----
  k_bnstats<<<256, 256, 0, stream>>>(out, mean2, istd2);
  k_lif<<<8192, 256, 0, stream>>>(out, mean2, istd2, bn2_g, bn2_b, spk);
  k_tr<<<dim3(256, 8, 2), 256, 0, stream>>>(spk, actT, 256, 8192, 2097152L, 2097152L);
  k_gffn1<<<dim3(8, 128), 256, 0, stream>>>(actT, w1T, ffn_b1, hbuf);
  k_gffn2<<<dim3(128, 8), 128, 0, stream>>>(w2T, hbuf, ffn_b2, scale, out);
}

// Round 4
// 336.780 us; speedup vs baseline: 2.7870x; 1.2662x over previous
//
#include <hip/hip_runtime.h>
#include <math.h>

#define CC 256
#define LL 8192
#define RR 32
#define PPP 256
#define NTOP 4

typedef unsigned short u16;
typedef __attribute__((ext_vector_type(8))) short short8;
typedef __attribute__((ext_vector_type(4))) float f32x4;
typedef __attribute__((ext_vector_type(4))) unsigned short u16x4;

__device__ inline u16 f2bf(float f) {
  unsigned int b = __float_as_uint(f);
  unsigned int r = (b + 0x7FFFu + ((b >> 16) & 1u)) >> 16;
  return (u16)r;
}
__device__ inline float bf2f(u16 x) { return __uint_as_float(((unsigned int)x) << 16); }

// ---------------- BN stats ----------------
__global__ __launch_bounds__(256) void k_bnstats(const float* __restrict__ x,
                                                 float* __restrict__ mean,
                                                 float* __restrict__ istd) {
  int c = blockIdx.x, tid = threadIdx.x;
  float s = 0.f, sq = 0.f;
  for (int i = tid; i < 2 * LL; i += 256) {
    int t = i >> 13, l = i & (LL - 1);
    float v = x[(t * CC + c) * LL + l];
    s += v; sq += v * v;
  }
  __shared__ float rs[256], rq[256];
  rs[tid] = s; rq[tid] = sq;
  __syncthreads();
  for (int off = 128; off > 0; off >>= 1) {
    if (tid < off) { rs[tid] += rs[tid + off]; rq[tid] += rq[tid + off]; }
    __syncthreads();
  }
  if (tid == 0) {
    float m = rs[0] * (1.f / (2 * LL));
    float var = rq[0] * (1.f / (2 * LL)) - m * m;
    mean[c] = m;
    istd[c] = rsqrtf(var + 1e-5f);
  }
}

// ---------------- fused BN + 2-step LIF + transpose -> actT bf16 [t][l][c] ----------------
__global__ __launch_bounds__(256) void k_lifT(const float* __restrict__ xin,
                                              const float* __restrict__ mean,
                                              const float* __restrict__ istd,
                                              const float* __restrict__ g,
                                              const float* __restrict__ b,
                                              u16* __restrict__ actT) {
  __shared__ float t0[32][33], t1[32][33];
  int l0 = blockIdx.x * 32, c0 = blockIdx.y * 32;
  int tx = threadIdx.x & 31, ty = threadIdx.x >> 5;
  for (int i = 0; i < 32; i += 8) {
    int c = c0 + ty + i;
    float m = mean[c], is = istd[c], gg = g[c], bb = b[c];
    float x0 = xin[(size_t)c * LL + l0 + tx];
    float x1 = xin[(size_t)(CC + c) * LL + l0 + tx];
    float y0 = gg * (x0 - m) * is + bb;
    float y1 = gg * (x1 - m) * is + bb;
    float v = y0 * 0.5f;
    float s0 = (v >= 1.f) ? 1.f : 0.f;
    v -= s0;
    v += (y1 - v) * 0.5f;
    float s1 = (v >= 1.f) ? 1.f : 0.f;
    t0[ty + i][tx] = s0;
    t1[ty + i][tx] = s1;
  }
  __syncthreads();
  for (int i = 0; i < 32; i += 8) {
    int l = l0 + ty + i;
    actT[(size_t)l * CC + c0 + tx] = f2bf(t0[tx][ty + i]);
    actT[(size_t)(LL + l) * CC + c0 + tx] = f2bf(t1[tx][ty + i]);
  }
}

// ---------------- fp32 [R][C] -> bf16 [C][R] transpose (weights) ----------------
__global__ __launch_bounds__(256) void k_tr(const float* __restrict__ in, u16* __restrict__ out,
                                            int R, int C, long ibs, long obs) {
  __shared__ float t[32][33];
  const float* ib = in + (size_t)blockIdx.z * ibs;
  u16* ob = out + (size_t)blockIdx.z * obs;
  int c0 = blockIdx.x * 32, r0 = blockIdx.y * 32;
  int tx = threadIdx.x & 31, ty = threadIdx.x >> 5;
  for (int i = 0; i < 32; i += 8)
    t[ty + i][tx] = ib[(size_t)(r0 + ty + i) * C + c0 + tx];
  __syncthreads();
  for (int i = 0; i < 32; i += 8)
    ob[(size_t)(c0 + ty + i) * R + r0 + tx] = f2bf(t[tx][ty + i]);
}

// ---------------- lepe weight transpose [256][27] -> fp32 [27][256] ----------------
__global__ __launch_bounds__(256) void k_trw(const float* __restrict__ w, float* __restrict__ wT) {
  int c = threadIdx.x;
  for (int tap = 0; tap < 27; ++tap) wT[tap * 256 + c] = w[c * 27 + tap];
}

// ---------------- MFMA core: D[m][n] += A[m][k]*B[n][k]^T, K-contiguous bf16 ----------------
template<int MR, int NR, int WCN>
__device__ inline void mfma_core(const u16* __restrict__ A0, int sA,
                                 const u16* __restrict__ B0, int sB,
                                 int K, f32x4 acc[MR][NR]) {
  int lane = threadIdx.x & 63;
  int w = threadIdx.x >> 6;
  int wr = w / WCN, wc = w % WCN;
  int rr = lane & 15;
  int g8 = (lane >> 4) * 8;
  const u16* Ap = A0 + (size_t)(wr * MR * 16 + rr) * sA + g8;
  const u16* Bp = B0 + (size_t)(wc * NR * 16 + rr) * sB + g8;
  for (int k0 = 0; k0 < K; k0 += 32) {
    short8 af[MR], bfr[NR];
#pragma unroll
    for (int i = 0; i < MR; ++i)
      af[i] = *(const short8*)(Ap + (size_t)i * 16 * sA + k0);
#pragma unroll
    for (int j = 0; j < NR; ++j)
      bfr[j] = *(const short8*)(Bp + (size_t)j * 16 * sB + k0);
#pragma unroll
    for (int i = 0; i < MR; ++i)
#pragma unroll
      for (int j = 0; j < NR; ++j)
        acc[i][j] = __builtin_amdgcn_mfma_f32_16x16x32_bf16(af[i], bfr[j], acc[i][j], 0, 0, 0);
  }
}

// ---------------- qkv GEMM -> bf16 per-head q/k, transposed v; fp32 v token-major ----------------
__global__ __launch_bounds__(256) void k_gqkv(const u16* __restrict__ spkT, const u16* __restrict__ wT,
                                              const float* __restrict__ bias,
                                              u16* __restrict__ qh, u16* __restrict__ kh,
                                              u16* __restrict__ vt, float* __restrict__ vtok) {
  f32x4 acc[4][4] = {};
  int n0 = blockIdx.x * 128, m0 = blockIdx.y * 128;
  mfma_core<4, 4, 2>(spkT + (size_t)m0 * 256, 256, wT + (size_t)n0 * 256, 256, 256, acc);
  int lane = threadIdx.x & 63, w = threadIdx.x >> 6;
  int wr = w >> 1, wc = w & 1;
  int u = lane & 15;
#pragma unroll
  for (int i = 0; i < 4; ++i) {
#pragma unroll
    for (int reg = 0; reg < 4; ++reg) {
      int token = m0 + wr * 64 + i * 16 + (lane >> 4) * 4 + reg;
      int l = token & (LL - 1), nb = token >> 13;
      int lt = l >> 10, lh = (l >> 5) & 31, lw = l & 31;
      int r = ((lt >> 2) * 4 + (lh >> 3)) * 4 + (lw >> 3);
      int p = ((lt & 3) * 8 + (lh & 7)) * 8 + (lw & 7);
      int nr = nb * RR + r;
#pragma unroll
      for (int j = 0; j < 4; ++j) {
        int ch = n0 + wc * 64 + j * 16 + u;
        float val = acc[i][j][reg] + bias[ch];
        int which = ch >> 8, c = ch & 255;
        int hh = c >> 5, dh = c & 31;
        size_t hb = ((size_t)nr * 8 + hh) * 8192;
        if (which == 0) {
          qh[hb + p * 32 + dh] = f2bf(val);
        } else if (which == 1) {
          kh[hb + p * 32 + dh] = f2bf(val);
        } else {
          vt[hb + dh * 256 + p] = f2bf(val);
          vtok[(size_t)token * CC + c] = val;
        }
      }
    }
  }
}

// ---------------- region means from bf16 heads ----------------
__global__ __launch_bounds__(256) void k_means(const u16* __restrict__ qh, const u16* __restrict__ kh,
                                               float* __restrict__ qm, float* __restrict__ km) {
  int nr = blockIdx.x, c = threadIdx.x;
  int hh = c >> 5, dh = c & 31;
  size_t base = ((size_t)nr * 8 + hh) * 8192 + dh;
  float sq = 0.f, sk = 0.f;
  for (int p = 0; p < 256; ++p) {
    sq += bf2f(qh[base + p * 32]);
    sk += bf2f(kh[base + p * 32]);
  }
  qm[nr * 256 + c] = sq * (1.f / 256);
  km[nr * 256 + c] = sk * (1.f / 256);
}

// ---------------- routing top-4 ----------------
__global__ __launch_bounds__(64) void k_route(const float* __restrict__ qm,
                                              const float* __restrict__ km,
                                              int* __restrict__ idx) {
  int nr = blockIdx.x;
  int n = nr >> 5;
  int tid = threadIdx.x;
  __shared__ float ar[32];
  if (tid < 32) {
    const float* qrow = qm + nr * CC;
    const float* krow = km + (n * RR + tid) * CC;
    float s = 0.f;
    for (int c = 0; c < CC; ++c) s += qrow[c] * krow[c];
    ar[tid] = s;
  }
  __syncthreads();
  if (tid == 0) {
    for (int t = 0; t < NTOP; ++t) {
      float best = -1e30f; int bi = 0;
      for (int s = 0; s < 32; ++s)
        if (ar[s] > best) { best = ar[s]; bi = s; }
      ar[bi] = -1e30f;
      idx[nr * NTOP + t] = bi;
    }
  }
}

// ---------------- MFMA flash attention: block (h, r, n), 4 waves x 64 q-rows ----------------
__global__ __launch_bounds__(256) void k_attn_mfma(const u16* __restrict__ qh,
                                                   const u16* __restrict__ kh,
                                                   const u16* __restrict__ vt,
                                                   const int* __restrict__ idx,
                                                   float* __restrict__ oreg) {
  int h = blockIdx.x, r = blockIdx.y, n = blockIdx.z;
  int nr = n * RR + r;
  int lane = threadIdx.x & 63;
  int w = threadIdx.x >> 6;
  int u = lane & 15, g = lane >> 4;
  const float qs = 0.17677669529663687f;  // 32^-0.5
  __shared__ u16 pl[4 * 2560];
  u16* plw = &pl[w * 2560];

  const u16* qb = qh + ((size_t)nr * 8 + h) * 8192;
  int q0 = w * 64;
  short8 qf[4];
#pragma unroll
  for (int f = 0; f < 4; ++f)
    qf[f] = *(const short8*)(qb + (size_t)(q0 + f * 16 + u) * 32 + g * 8);

  f32x4 accO[2][4] = {};
  float lsum[4] = {0.f, 0.f, 0.f, 0.f};
  const int* idxp = &idx[nr * NTOP];

  for (int kt = 0; kt < 32; ++kt) {
    int reg = idxp[kt >> 3];
    int pb = (kt & 7) * 32;
    size_t rb = ((size_t)(n * RR + reg) * 8 + h) * 8192;
    short8 kf0 = *(const short8*)(kh + rb + (size_t)(pb + u) * 32 + g * 8);
    short8 kf1 = *(const short8*)(kh + rb + (size_t)(pb + 16 + u) * 32 + g * 8);
    short8 vf0 = *(const short8*)(vt + rb + (size_t)(u) * 256 + pb + g * 8);
    short8 vf1 = *(const short8*)(vt + rb + (size_t)(16 + u) * 256 + pb + g * 8);

    f32x4 s[2][4];
#pragma unroll
    for (int nf = 0; nf < 4; ++nf) {
      s[0][nf] = __builtin_amdgcn_mfma_f32_16x16x32_bf16(kf0, qf[nf], (f32x4){0.f, 0.f, 0.f, 0.f}, 0, 0, 0);
      s[1][nf] = __builtin_amdgcn_mfma_f32_16x16x32_bf16(kf1, qf[nf], (f32x4){0.f, 0.f, 0.f, 0.f}, 0, 0, 0);
    }
#pragma unroll
    for (int nf = 0; nf < 4; ++nf) {
#pragma unroll
      for (int mf = 0; mf < 2; ++mf) {
        u16 b0 = f2bf(__expf(s[mf][nf][0] * qs));
        u16 b1 = f2bf(__expf(s[mf][nf][1] * qs));
        u16 b2 = f2bf(__expf(s[mf][nf][2] * qs));
        u16 b3 = f2bf(__expf(s[mf][nf][3] * qs));
        lsum[nf] += (bf2f(b0) + bf2f(b1)) + (bf2f(b2) + bf2f(b3));
        *(u16x4*)&plw[(nf * 16 + u) * 40 + mf * 16 + g * 4] = (u16x4){b0, b1, b2, b3};
      }
    }
#pragma unroll
    for (int nf = 0; nf < 4; ++nf) {
      short8 pf = *(const short8*)&plw[(nf * 16 + u) * 40 + g * 8];
      accO[0][nf] = __builtin_amdgcn_mfma_f32_16x16x32_bf16(vf0, pf, accO[0][nf], 0, 0, 0);
      accO[1][nf] = __builtin_amdgcn_mfma_f32_16x16x32_bf16(vf1, pf, accO[1][nf], 0, 0, 0);
    }
  }

#pragma unroll
  for (int nf = 0; nf < 4; ++nf) {
    lsum[nf] += __shfl_xor(lsum[nf], 16);
    lsum[nf] += __shfl_xor(lsum[nf], 32);
    float inv = 1.f / lsum[nf];
    int q = q0 + nf * 16 + u;
    // (r, p=q) -> token-major l via bit permutation
    int z = (((r >> 4) & 1) << 2) | ((q >> 6) & 3);
    int y = (((r >> 2) & 3) << 3) | ((q >> 3) & 7);
    int xx = ((r & 3) << 3) | (q & 7);
    int l = (z << 10) | (y << 5) | xx;
    float* ob = &oreg[((size_t)(n * LL + l)) * CC + h * 32];
#pragma unroll
    for (int mf = 0; mf < 2; ++mf) {
      f32x4 o = accO[mf][nf];
      *(float4*)&ob[mf * 16 + g * 4] =
          make_float4(o[0] * inv, o[1] * inv, o[2] * inv, o[3] * inv);
    }
  }
}

// ---------------- LEPE stencil, token-major, one voxel per block ----------------
__global__ __launch_bounds__(256) void k_lepe(const float* __restrict__ oreg,
                                              const float* __restrict__ vtok,
                                              const float* __restrict__ wT,
                                              u16* __restrict__ otok) {
  int b = blockIdx.x;                 // n*8192 + l
  int l = b & (LL - 1);
  int lt = l >> 10, lh = (l >> 5) & 31, lw = l & 31;
  int c = threadIdx.x;
  const float* vb = vtok + (size_t)b * CC + c;
  float lep = 0.f;
#pragma unroll
  for (int dz = -1; dz <= 1; ++dz) {
#pragma unroll
    for (int dy = -1; dy <= 1; ++dy) {
#pragma unroll
      for (int dx = -1; dx <= 1; ++dx) {
        int z = lt + dz, y = lh + dy, xx = lw + dx;
        if (z >= 0 && z < 8 && y >= 0 && y < 32 && xx >= 0 && xx < 32) {
          int tap = ((dz + 1) * 3 + (dy + 1)) * 3 + (dx + 1);
          long off = (long)(dz * 1024 + dy * 32 + dx) * CC;
          lep = fmaf(wT[tap * 256 + c], vb[off], lep);
        }
      }
    }
  }
  float acc = oreg[(size_t)b * CC + c];
  otok[(size_t)b * CC + c] = f2bf(acc + lep);
}

// ---------------- FFN1 GEMM -> GELU -> hbuf bf16 ----------------
__global__ __launch_bounds__(256) void k_gffn1(const u16* __restrict__ sT, const u16* __restrict__ wT,
                                               const float* __restrict__ bias, u16* __restrict__ hbuf) {
  f32x4 acc[4][4] = {};
  int n0 = blockIdx.x * 128, m0 = blockIdx.y * 128;
  mfma_core<4, 4, 2>(sT + (size_t)m0 * 256, 256, wT + (size_t)n0 * 256, 256, 256, acc);
  int lane = threadIdx.x & 63, w = threadIdx.x >> 6;
  int wr = w >> 1, wc = w & 1;
#pragma unroll
  for (int i = 0; i < 4; ++i) {
#pragma unroll
    for (int reg = 0; reg < 4; ++reg) {
      int token = m0 + wr * 64 + i * 16 + (lane >> 4) * 4 + reg;
#pragma unroll
      for (int j = 0; j < 4; ++j) {
        int ch = n0 + wc * 64 + j * 16 + (lane & 15);
        float z = acc[i][j][reg] + bias[ch];
        float gel = 0.5f * z * (1.f + erff(z * 0.70710678118654752f));
        hbuf[(size_t)token * 1024 + ch] = f2bf(gel);
      }
    }
  }
}

// ---------------- FFN2 GEMM (output-transposed): out[t][c][l] += (W2^T h + b2)*sc ----------------
__global__ __launch_bounds__(128) void k_gffn2(const u16* __restrict__ w2T, const u16* __restrict__ hb,
                                               const float* __restrict__ bias, const float* __restrict__ scale,
                                               float* __restrict__ out) {
  f32x4 acc[2][4] = {};
  int n0 = blockIdx.x * 128, m0 = blockIdx.y * 32;
  mfma_core<2, 4, 2>(w2T + (size_t)m0 * 1024, 1024, hb + (size_t)n0 * 1024, 1024, 1024, acc);
  int lane = threadIdx.x & 63, wc = threadIdx.x >> 6;
  float sc = scale[0];
#pragma unroll
  for (int i = 0; i < 2; ++i) {
#pragma unroll
    for (int reg = 0; reg < 4; ++reg) {
      int ch = m0 + i * 16 + (lane >> 4) * 4 + reg;
      float bb = bias[ch];
#pragma unroll
      for (int j = 0; j < 4; ++j) {
        int token = n0 + wc * 64 + j * 16 + (lane & 15);
        int t = token >> 13, l = token & (LL - 1);
        size_t oi = ((size_t)t * CC + ch) * LL + l;
        out[oi] += (acc[i][j][reg] + bb) * sc;
      }
    }
  }
}

// ---------------- Wo GEMM (output-transposed): out[t][c][l] = x + (Wo^T a + bo)*sc ----------------
__global__ __launch_bounds__(128) void k_gwo(const u16* __restrict__ woT, const u16* __restrict__ atok,
                                             const float* __restrict__ bias, const float* __restrict__ xin,
                                             const float* __restrict__ scale, float* __restrict__ out) {
  f32x4 acc[2][4] = {};
  int n0 = blockIdx.x * 128, m0 = blockIdx.y * 32;
  mfma_core<2, 4, 2>(woT + (size_t)m0 * 256, 256, atok + (size_t)n0 * 256, 256, 256, acc);
  int lane = threadIdx.x & 63, wc = threadIdx.x >> 6;
  float sc = scale[0];
#pragma unroll
  for (int i = 0; i < 2; ++i) {
#pragma unroll
    for (int reg = 0; reg < 4; ++reg) {
      int ch = m0 + i * 16 + (lane >> 4) * 4 + reg;
      float bb = bias[ch];
#pragma unroll
      for (int j = 0; j < 4; ++j) {
        int token = n0 + wc * 64 + j * 16 + (lane & 15);
        int t = token >> 13, l = token & (LL - 1);
        size_t oi = ((size_t)t * CC + ch) * LL + l;
        out[oi] = xin[oi] + (acc[i][j][reg] + bb) * sc;
      }
    }
  }
}

extern "C" void kernel_launch(void* const* d_in, const int* in_sizes, int n_in,
                              void* d_out, int out_size, void* d_ws, size_t ws_size,
                              hipStream_t stream) {
  const float* x      = (const float*)d_in[0];
  const float* bn1_g  = (const float*)d_in[1];
  const float* bn1_b  = (const float*)d_in[2];
  const float* wqkv   = (const float*)d_in[3];
  const float* bqkv   = (const float*)d_in[4];
  const float* lepe_w = (const float*)d_in[5];
  const float* wo_w   = (const float*)d_in[6];
  const float* bo     = (const float*)d_in[7];
  const float* bn2_g  = (const float*)d_in[8];
  const float* bn2_b  = (const float*)d_in[9];
  const float* ffn_w1 = (const float*)d_in[10];
  const float* ffn_b1 = (const float*)d_in[11];
  const float* ffn_w2 = (const float*)d_in[12];
  const float* ffn_b2 = (const float*)d_in[13];
  const float* scale  = (const float*)d_in[14];
  float* out = (float*)d_out;

  float* ws    = (float*)d_ws;
  u16*   actT  = (u16*)(ws + 4194304);         // 4M u16: spkT / otok / s2T
  u16*   qhead = (u16*)(ws + 6291456);         // 4M u16
  u16*   khead = (u16*)(ws + 8388608);         // 4M u16
  u16*   vthead= (u16*)(ws + 10485760);        // 4M u16
  float* vtok  = ws + 12582912;                // 4M fl (token-major fp32 v)
  float* oreg  = ws + 16777216;                // 4M fl (token-major attn out)
  u16*   hbuf  = (u16*)(ws + 6291456);         // 16M u16, overlaps qhead..vtok (dead in FFN)
  u16*   wqkvT = (u16*)(ws + 20971520);
  u16*   w1T   = (u16*)(ws + 21069824);
  u16*   w2T   = (u16*)(ws + 21200896);
  u16*   woT   = (u16*)(ws + 21331968);
  float* sm    = ws + 21364736;
  float* mean1 = sm;
  float* istd1 = sm + 256;
  float* mean2 = sm + 512;
  float* istd2 = sm + 768;
  float* qm    = sm + 1024;
  float* km    = sm + 1024 + 16384;
  int*   idxb  = (int*)(sm + 1024 + 32768);
  float* wTlep = sm + 1024 + 32768 + 256;      // 27*256 fp32

  // weight transposes
  k_tr<<<dim3(24, 8, 1), 256, 0, stream>>>(wqkv, wqkvT, 256, 768, 0, 0);
  k_tr<<<dim3(32, 8, 1), 256, 0, stream>>>(ffn_w1, w1T, 256, 1024, 0, 0);
  k_tr<<<dim3(8, 32, 1), 256, 0, stream>>>(ffn_w2, w2T, 1024, 256, 0, 0);
  k_tr<<<dim3(8, 8, 1), 256, 0, stream>>>(wo_w, woT, 256, 256, 0, 0);
  k_trw<<<1, 256, 0, stream>>>(lepe_w, wTlep);

  // ---- attention branch ----
  k_bnstats<<<256, 256, 0, stream>>>(x, mean1, istd1);
  k_lifT<<<dim3(256, 8), 256, 0, stream>>>(x, mean1, istd1, bn1_g, bn1_b, actT);
  k_gqkv<<<dim3(6, 128), 256, 0, stream>>>(actT, wqkvT, bqkv, qhead, khead, vthead, vtok);
  k_means<<<64, 256, 0, stream>>>(qhead, khead, qm, km);
  k_route<<<64, 64, 0, stream>>>(qm, km, idxb);
  k_attn_mfma<<<dim3(8, RR, 2), 256, 0, stream>>>(qhead, khead, vthead, idxb, oreg);
  k_lepe<<<16384, 256, 0, stream>>>(oreg, vtok, wTlep, actT);
  k_gwo<<<dim3(128, 8), 128, 0, stream>>>(woT, actT, bo, x, scale, out);

  // ---- FFN branch ----
  k_bnstats<<<256, 256, 0, stream>>>(out, mean2, istd2);
  k_lifT<<<dim3(256, 8), 256, 0, stream>>>(out, mean2, istd2, bn2_g, bn2_b, actT);
  k_gffn1<<<dim3(8, 128), 256, 0, stream>>>(actT, w1T, ffn_b1, hbuf);
  k_gffn2<<<dim3(128, 8), 128, 0, stream>>>(w2T, hbuf, ffn_b2, scale, out);
}

// Round 5
// 275.997 us; speedup vs baseline: 3.4008x; 1.2202x over previous
//
#include <hip/hip_runtime.h>
#include <math.h>

#define CC 256
#define LL 8192
#define RR 32
#define PPP 256
#define NTOP 4

typedef unsigned short u16;
typedef __attribute__((ext_vector_type(8))) short short8;
typedef __attribute__((ext_vector_type(4))) float f32x4;
typedef __attribute__((ext_vector_type(4))) unsigned short u16x4;

__device__ inline u16 f2bf(float f) {
  unsigned int b = __float_as_uint(f);
  unsigned int r = (b + 0x7FFFu + ((b >> 16) & 1u)) >> 16;
  return (u16)r;
}
__device__ inline float bf2f(u16 x) { return __uint_as_float(((unsigned int)x) << 16); }

// ---------------- BN stats ----------------
__global__ __launch_bounds__(256) void k_bnstats(const float* __restrict__ x,
                                                 float* __restrict__ mean,
                                                 float* __restrict__ istd) {
  int c = blockIdx.x, tid = threadIdx.x;
  float s = 0.f, sq = 0.f;
  for (int i = tid; i < 2 * LL / 4; i += 256) {
    int t = i >> 11, l4 = (i & 2047) * 4;
    float4 v = *(const float4*)&x[(size_t)(t * CC + c) * LL + l4];
    s += (v.x + v.y) + (v.z + v.w);
    sq += (v.x * v.x + v.y * v.y) + (v.z * v.z + v.w * v.w);
  }
  __shared__ float rs[256], rq[256];
  rs[tid] = s; rq[tid] = sq;
  __syncthreads();
  for (int off = 128; off > 0; off >>= 1) {
    if (tid < off) { rs[tid] += rs[tid + off]; rq[tid] += rq[tid + off]; }
    __syncthreads();
  }
  if (tid == 0) {
    float m = rs[0] * (1.f / (2 * LL));
    float var = rq[0] * (1.f / (2 * LL)) - m * m;
    mean[c] = m;
    istd[c] = rsqrtf(var + 1e-5f);
  }
}

// ---------------- fused BN + 2-step LIF + transpose -> actT bf16 [t][l][c] ----------------
__global__ __launch_bounds__(256) void k_lifT(const float* __restrict__ xin,
                                              const float* __restrict__ mean,
                                              const float* __restrict__ istd,
                                              const float* __restrict__ g,
                                              const float* __restrict__ b,
                                              u16* __restrict__ actT) {
  __shared__ float t0[32][33], t1[32][33];
  int l0 = blockIdx.x * 32, c0 = blockIdx.y * 32;
  int tx = threadIdx.x & 31, ty = threadIdx.x >> 5;
  for (int i = 0; i < 32; i += 8) {
    int c = c0 + ty + i;
    float m = mean[c], is = istd[c], gg = g[c], bb = b[c];
    float x0 = xin[(size_t)c * LL + l0 + tx];
    float x1 = xin[(size_t)(CC + c) * LL + l0 + tx];
    float y0 = gg * (x0 - m) * is + bb;
    float y1 = gg * (x1 - m) * is + bb;
    float v = y0 * 0.5f;
    float s0 = (v >= 1.f) ? 1.f : 0.f;
    v -= s0;
    v += (y1 - v) * 0.5f;
    float s1 = (v >= 1.f) ? 1.f : 0.f;
    t0[ty + i][tx] = s0;
    t1[ty + i][tx] = s1;
  }
  __syncthreads();
  for (int i = 0; i < 32; i += 8) {
    int l = l0 + ty + i;
    actT[(size_t)l * CC + c0 + tx] = f2bf(t0[tx][ty + i]);
    actT[(size_t)(LL + l) * CC + c0 + tx] = f2bf(t1[tx][ty + i]);
  }
}

// ---------------- fp32 [R][C] -> bf16 [C][R] transpose (weights) ----------------
__global__ __launch_bounds__(256) void k_tr(const float* __restrict__ in, u16* __restrict__ out,
                                            int R, int C, long ibs, long obs) {
  __shared__ float t[32][33];
  const float* ib = in + (size_t)blockIdx.z * ibs;
  u16* ob = out + (size_t)blockIdx.z * obs;
  int c0 = blockIdx.x * 32, r0 = blockIdx.y * 32;
  int tx = threadIdx.x & 31, ty = threadIdx.x >> 5;
  for (int i = 0; i < 32; i += 8)
    t[ty + i][tx] = ib[(size_t)(r0 + ty + i) * C + c0 + tx];
  __syncthreads();
  for (int i = 0; i < 32; i += 8)
    ob[(size_t)(c0 + ty + i) * R + r0 + tx] = f2bf(t[tx][ty + i]);
}

// ---------------- lepe weight transpose [256][27] -> fp32 [27][256] ----------------
__global__ __launch_bounds__(256) void k_trw(const float* __restrict__ w, float* __restrict__ wT) {
  int c = threadIdx.x;
  for (int tap = 0; tap < 27; ++tap) wT[tap * 256 + c] = w[c * 27 + tap];
}

// ---------------- MFMA core: D[m][n] += A[m][k]*B[n][k]^T, K-contiguous bf16 ----------------
template<int MR, int NR, int WCN>
__device__ inline void mfma_core(const u16* __restrict__ A0, int sA,
                                 const u16* __restrict__ B0, int sB,
                                 int K, f32x4 acc[MR][NR]) {
  int lane = threadIdx.x & 63;
  int w = threadIdx.x >> 6;
  int wr = w / WCN, wc = w % WCN;
  int rr = lane & 15;
  int g8 = (lane >> 4) * 8;
  const u16* Ap = A0 + (size_t)(wr * MR * 16 + rr) * sA + g8;
  const u16* Bp = B0 + (size_t)(wc * NR * 16 + rr) * sB + g8;
  for (int k0 = 0; k0 < K; k0 += 32) {
    short8 af[MR], bfr[NR];
#pragma unroll
    for (int i = 0; i < MR; ++i)
      af[i] = *(const short8*)(Ap + (size_t)i * 16 * sA + k0);
#pragma unroll
    for (int j = 0; j < NR; ++j)
      bfr[j] = *(const short8*)(Bp + (size_t)j * 16 * sB + k0);
#pragma unroll
    for (int i = 0; i < MR; ++i)
#pragma unroll
      for (int j = 0; j < NR; ++j)
        acc[i][j] = __builtin_amdgcn_mfma_f32_16x16x32_bf16(af[i], bfr[j], acc[i][j], 0, 0, 0);
  }
}

// ---------------- qkv GEMM -> bf16 per-head q/k, transposed v; fp32 v token-major ----------------
__global__ __launch_bounds__(256) void k_gqkv(const u16* __restrict__ spkT, const u16* __restrict__ wT,
                                              const float* __restrict__ bias,
                                              u16* __restrict__ qh, u16* __restrict__ kh,
                                              u16* __restrict__ vt, float* __restrict__ vtok) {
  f32x4 acc[4][4] = {};
  int n0 = blockIdx.x * 128, m0 = blockIdx.y * 128;
  mfma_core<4, 4, 2>(spkT + (size_t)m0 * 256, 256, wT + (size_t)n0 * 256, 256, 256, acc);
  int lane = threadIdx.x & 63, w = threadIdx.x >> 6;
  int wr = w >> 1, wc = w & 1;
  int u = lane & 15;
#pragma unroll
  for (int i = 0; i < 4; ++i) {
#pragma unroll
    for (int reg = 0; reg < 4; ++reg) {
      int token = m0 + wr * 64 + i * 16 + (lane >> 4) * 4 + reg;
      int l = token & (LL - 1), nb = token >> 13;
      int lt = l >> 10, lh = (l >> 5) & 31, lw = l & 31;
      int r = ((lt >> 2) * 4 + (lh >> 3)) * 4 + (lw >> 3);
      int p = ((lt & 3) * 8 + (lh & 7)) * 8 + (lw & 7);
      int nr = nb * RR + r;
#pragma unroll
      for (int j = 0; j < 4; ++j) {
        int ch = n0 + wc * 64 + j * 16 + u;
        float val = acc[i][j][reg] + bias[ch];
        int which = ch >> 8, c = ch & 255;
        int hh = c >> 5, dh = c & 31;
        size_t hb = ((size_t)nr * 8 + hh) * 8192;
        if (which == 0) {
          qh[hb + p * 32 + dh] = f2bf(val);
        } else if (which == 1) {
          kh[hb + p * 32 + dh] = f2bf(val);
        } else {
          vt[hb + dh * 256 + p] = f2bf(val);
          vtok[(size_t)token * CC + c] = val;
        }
      }
    }
  }
}

// ---------------- region means: block per (nr, h) ----------------
__global__ __launch_bounds__(256) void k_means(const u16* __restrict__ qh, const u16* __restrict__ kh,
                                               float* __restrict__ qm, float* __restrict__ km) {
  int nrh = blockIdx.x;               // nr*8 + h
  int nr = nrh >> 3, h = nrh & 7;
  int tid = threadIdx.x;
  int dh = tid & 31, pg = tid >> 5;   // 8 p-groups
  size_t base = (size_t)nrh * 8192;
  float sq = 0.f, sk = 0.f;
  for (int p = pg * 32; p < pg * 32 + 32; ++p) {
    sq += bf2f(qh[base + p * 32 + dh]);
    sk += bf2f(kh[base + p * 32 + dh]);
  }
  __shared__ float rq[256], rk[256];
  rq[tid] = sq; rk[tid] = sk;
  __syncthreads();
  if (pg == 0) {
#pragma unroll
    for (int g = 1; g < 8; ++g) { sq += rq[g * 32 + dh]; sk += rk[g * 32 + dh]; }
    qm[nr * 256 + h * 32 + dh] = sq * (1.f / 256);
    km[nr * 256 + h * 32 + dh] = sk * (1.f / 256);
  }
}

// ---------------- routing top-4: 8 lanes per candidate region ----------------
__global__ __launch_bounds__(256) void k_route(const float* __restrict__ qm,
                                               const float* __restrict__ km,
                                               int* __restrict__ idx) {
  int nr = blockIdx.x;
  int n = nr >> 5;
  int tid = threadIdx.x;
  int s = tid >> 3, cg = tid & 7;
  const float* qrow = qm + nr * CC;
  const float* krow = km + (n * RR + s) * CC;
  float sum = 0.f;
  for (int c = cg * 32; c < cg * 32 + 32; ++c) sum += qrow[c] * krow[c];
  sum += __shfl_xor(sum, 1);
  sum += __shfl_xor(sum, 2);
  sum += __shfl_xor(sum, 4);
  __shared__ float ar[32];
  if (cg == 0) ar[s] = sum;
  __syncthreads();
  if (tid == 0) {
    for (int t = 0; t < NTOP; ++t) {
      float best = -1e30f; int bi = 0;
      for (int ss = 0; ss < 32; ++ss)
        if (ar[ss] > best) { best = ar[ss]; bi = ss; }
      ar[bi] = -1e30f;
      idx[nr * NTOP + t] = bi;
    }
  }
}

// ---------------- MFMA flash attention: block (h, r, n), 4 waves x 64 q-rows ----------------
__global__ __launch_bounds__(256) void k_attn_mfma(const u16* __restrict__ qh,
                                                   const u16* __restrict__ kh,
                                                   const u16* __restrict__ vt,
                                                   const int* __restrict__ idx,
                                                   float* __restrict__ oreg) {
  int h = blockIdx.x, r = blockIdx.y, n = blockIdx.z;
  int nr = n * RR + r;
  int lane = threadIdx.x & 63;
  int w = threadIdx.x >> 6;
  int u = lane & 15, g = lane >> 4;
  const float qs = 0.17677669529663687f;  // 32^-0.5
  __shared__ u16 pl[4 * 2560];
  u16* plw = &pl[w * 2560];

  const u16* qb = qh + ((size_t)nr * 8 + h) * 8192;
  int q0 = w * 64;
  short8 qf[4];
#pragma unroll
  for (int f = 0; f < 4; ++f)
    qf[f] = *(const short8*)(qb + (size_t)(q0 + f * 16 + u) * 32 + g * 8);

  f32x4 accO[2][4] = {};
  float lsum[4] = {0.f, 0.f, 0.f, 0.f};
  const int* idxp = &idx[nr * NTOP];

  for (int kt = 0; kt < 32; ++kt) {
    int reg = idxp[kt >> 3];
    int pb = (kt & 7) * 32;
    size_t rb = ((size_t)(n * RR + reg) * 8 + h) * 8192;
    short8 kf0 = *(const short8*)(kh + rb + (size_t)(pb + u) * 32 + g * 8);
    short8 kf1 = *(const short8*)(kh + rb + (size_t)(pb + 16 + u) * 32 + g * 8);
    short8 vf0 = *(const short8*)(vt + rb + (size_t)(u) * 256 + pb + g * 8);
    short8 vf1 = *(const short8*)(vt + rb + (size_t)(16 + u) * 256 + pb + g * 8);

    f32x4 s[2][4];
#pragma unroll
    for (int nf = 0; nf < 4; ++nf) {
      s[0][nf] = __builtin_amdgcn_mfma_f32_16x16x32_bf16(kf0, qf[nf], (f32x4){0.f, 0.f, 0.f, 0.f}, 0, 0, 0);
      s[1][nf] = __builtin_amdgcn_mfma_f32_16x16x32_bf16(kf1, qf[nf], (f32x4){0.f, 0.f, 0.f, 0.f}, 0, 0, 0);
    }
#pragma unroll
    for (int nf = 0; nf < 4; ++nf) {
#pragma unroll
      for (int mf = 0; mf < 2; ++mf) {
        u16 b0 = f2bf(__expf(s[mf][nf][0] * qs));
        u16 b1 = f2bf(__expf(s[mf][nf][1] * qs));
        u16 b2 = f2bf(__expf(s[mf][nf][2] * qs));
        u16 b3 = f2bf(__expf(s[mf][nf][3] * qs));
        lsum[nf] += (bf2f(b0) + bf2f(b1)) + (bf2f(b2) + bf2f(b3));
        *(u16x4*)&plw[(nf * 16 + u) * 40 + mf * 16 + g * 4] = (u16x4){b0, b1, b2, b3};
      }
    }
#pragma unroll
    for (int nf = 0; nf < 4; ++nf) {
      short8 pf = *(const short8*)&plw[(nf * 16 + u) * 40 + g * 8];
      accO[0][nf] = __builtin_amdgcn_mfma_f32_16x16x32_bf16(vf0, pf, accO[0][nf], 0, 0, 0);
      accO[1][nf] = __builtin_amdgcn_mfma_f32_16x16x32_bf16(vf1, pf, accO[1][nf], 0, 0, 0);
    }
  }

#pragma unroll
  for (int nf = 0; nf < 4; ++nf) {
    lsum[nf] += __shfl_xor(lsum[nf], 16);
    lsum[nf] += __shfl_xor(lsum[nf], 32);
    float inv = 1.f / lsum[nf];
    int q = q0 + nf * 16 + u;
    int z = (((r >> 4) & 1) << 2) | ((q >> 6) & 3);
    int y = (((r >> 2) & 3) << 3) | ((q >> 3) & 7);
    int xx = ((r & 3) << 3) | (q & 7);
    int l = (z << 10) | (y << 5) | xx;
    float* ob = &oreg[((size_t)(n * LL + l)) * CC + h * 32];
#pragma unroll
    for (int mf = 0; mf < 2; ++mf) {
      f32x4 o = accO[mf][nf];
      *(float4*)&ob[mf * 16 + g * 4] =
          make_float4(o[0] * inv, o[1] * inv, o[2] * inv, o[3] * inv);
    }
  }
}

// ---------------- LEPE stencil, token-major, 4 voxels/block, float4/thread ----------------
__global__ __launch_bounds__(256) void k_lepe(const float* __restrict__ oreg,
                                              const float* __restrict__ vtok,
                                              const float* __restrict__ wT,
                                              u16* __restrict__ otok) {
  int vox = threadIdx.x >> 6;
  int b = blockIdx.x * 4 + vox;       // n*8192 + l
  int l = b & (LL - 1);
  int lt = l >> 10, lh = (l >> 5) & 31, lw = l & 31;
  int c4 = (threadIdx.x & 63) * 4;
  const float* vb = vtok + (size_t)b * CC + c4;
  float lx = 0.f, ly = 0.f, lz = 0.f, lww = 0.f;
#pragma unroll
  for (int dz = -1; dz <= 1; ++dz) {
#pragma unroll
    for (int dy = -1; dy <= 1; ++dy) {
#pragma unroll
      for (int dx = -1; dx <= 1; ++dx) {
        int z = lt + dz, y = lh + dy, xx = lw + dx;
        if (z >= 0 && z < 8 && y >= 0 && y < 32 && xx >= 0 && xx < 32) {
          int tap = ((dz + 1) * 3 + (dy + 1)) * 3 + (dx + 1);
          long off = (long)(dz * 1024 + dy * 32 + dx) * CC;
          float4 w4 = *(const float4*)&wT[tap * 256 + c4];
          float4 v4 = *(const float4*)&vb[off];
          lx = fmaf(w4.x, v4.x, lx);
          ly = fmaf(w4.y, v4.y, ly);
          lz = fmaf(w4.z, v4.z, lz);
          lww = fmaf(w4.w, v4.w, lww);
        }
      }
    }
  }
  float4 acc = *(const float4*)&oreg[(size_t)b * CC + c4];
  *(u16x4*)&otok[(size_t)b * CC + c4] =
      (u16x4){f2bf(acc.x + lx), f2bf(acc.y + ly), f2bf(acc.z + lz), f2bf(acc.w + lww)};
}

// ---------------- FFN1 GEMM -> GELU -> hbuf bf16 ----------------
__global__ __launch_bounds__(256) void k_gffn1(const u16* __restrict__ sT, const u16* __restrict__ wT,
                                               const float* __restrict__ bias, u16* __restrict__ hbuf) {
  f32x4 acc[4][4] = {};
  int n0 = blockIdx.x * 128, m0 = blockIdx.y * 128;
  mfma_core<4, 4, 2>(sT + (size_t)m0 * 256, 256, wT + (size_t)n0 * 256, 256, 256, acc);
  int lane = threadIdx.x & 63, w = threadIdx.x >> 6;
  int wr = w >> 1, wc = w & 1;
#pragma unroll
  for (int i = 0; i < 4; ++i) {
#pragma unroll
    for (int reg = 0; reg < 4; ++reg) {
      int token = m0 + wr * 64 + i * 16 + (lane >> 4) * 4 + reg;
#pragma unroll
      for (int j = 0; j < 4; ++j) {
        int ch = n0 + wc * 64 + j * 16 + (lane & 15);
        float z = acc[i][j][reg] + bias[ch];
        float gel = 0.5f * z * (1.f + erff(z * 0.70710678118654752f));
        hbuf[(size_t)token * 1024 + ch] = f2bf(gel);
      }
    }
  }
}

// ---------------- FFN2 GEMM (output-transposed): out[t][c][l] += (W2^T h + b2)*sc ----------------
__global__ __launch_bounds__(128) void k_gffn2(const u16* __restrict__ w2T, const u16* __restrict__ hb,
                                               const float* __restrict__ bias, const float* __restrict__ scale,
                                               float* __restrict__ out) {
  f32x4 acc[2][4] = {};
  int n0 = blockIdx.x * 128, m0 = blockIdx.y * 32;
  mfma_core<2, 4, 2>(w2T + (size_t)m0 * 1024, 1024, hb + (size_t)n0 * 1024, 1024, 1024, acc);
  int lane = threadIdx.x & 63, wc = threadIdx.x >> 6;
  float sc = scale[0];
#pragma unroll
  for (int i = 0; i < 2; ++i) {
#pragma unroll
    for (int reg = 0; reg < 4; ++reg) {
      int ch = m0 + i * 16 + (lane >> 4) * 4 + reg;
      float bb = bias[ch];
#pragma unroll
      for (int j = 0; j < 4; ++j) {
        int token = n0 + wc * 64 + j * 16 + (lane & 15);
        int t = token >> 13, l = token & (LL - 1);
        size_t oi = ((size_t)t * CC + ch) * LL + l;
        out[oi] += (acc[i][j][reg] + bb) * sc;
      }
    }
  }
}

// ---------------- Wo GEMM (output-transposed): out[t][c][l] = x + (Wo^T a + bo)*sc ----------------
__global__ __launch_bounds__(128) void k_gwo(const u16* __restrict__ woT, const u16* __restrict__ atok,
                                             const float* __restrict__ bias, const float* __restrict__ xin,
                                             const float* __restrict__ scale, float* __restrict__ out) {
  f32x4 acc[2][4] = {};
  int n0 = blockIdx.x * 128, m0 = blockIdx.y * 32;
  mfma_core<2, 4, 2>(woT + (size_t)m0 * 256, 256, atok + (size_t)n0 * 256, 256, 256, acc);
  int lane = threadIdx.x & 63, wc = threadIdx.x >> 6;
  float sc = scale[0];
#pragma unroll
  for (int i = 0; i < 2; ++i) {
#pragma unroll
    for (int reg = 0; reg < 4; ++reg) {
      int ch = m0 + i * 16 + (lane >> 4) * 4 + reg;
      float bb = bias[ch];
#pragma unroll
      for (int j = 0; j < 4; ++j) {
        int token = n0 + wc * 64 + j * 16 + (lane & 15);
        int t = token >> 13, l = token & (LL - 1);
        size_t oi = ((size_t)t * CC + ch) * LL + l;
        out[oi] = xin[oi] + (acc[i][j][reg] + bb) * sc;
      }
    }
  }
}

extern "C" void kernel_launch(void* const* d_in, const int* in_sizes, int n_in,
                              void* d_out, int out_size, void* d_ws, size_t ws_size,
                              hipStream_t stream) {
  const float* x      = (const float*)d_in[0];
  const float* bn1_g  = (const float*)d_in[1];
  const float* bn1_b  = (const float*)d_in[2];
  const float* wqkv   = (const float*)d_in[3];
  const float* bqkv   = (const float*)d_in[4];
  const float* lepe_w = (const float*)d_in[5];
  const float* wo_w   = (const float*)d_in[6];
  const float* bo     = (const float*)d_in[7];
  const float* bn2_g  = (const float*)d_in[8];
  const float* bn2_b  = (const float*)d_in[9];
  const float* ffn_w1 = (const float*)d_in[10];
  const float* ffn_b1 = (const float*)d_in[11];
  const float* ffn_w2 = (const float*)d_in[12];
  const float* ffn_b2 = (const float*)d_in[13];
  const float* scale  = (const float*)d_in[14];
  float* out = (float*)d_out;

  float* ws    = (float*)d_ws;
  u16*   actT  = (u16*)(ws + 4194304);         // 4M u16: spkT / otok / s2T
  u16*   qhead = (u16*)(ws + 6291456);         // 4M u16
  u16*   khead = (u16*)(ws + 8388608);         // 4M u16
  u16*   vthead= (u16*)(ws + 10485760);        // 4M u16
  float* vtok  = ws + 12582912;                // 4M fl (token-major fp32 v)
  float* oreg  = ws + 16777216;                // 4M fl (token-major attn out)
  u16*   hbuf  = (u16*)(ws + 6291456);         // 16M u16, overlaps qhead..vtok (dead in FFN)
  u16*   wqkvT = (u16*)(ws + 20971520);
  u16*   w1T   = (u16*)(ws + 21069824);
  u16*   w2T   = (u16*)(ws + 21200896);
  u16*   woT   = (u16*)(ws + 21331968);
  float* sm    = ws + 21364736;
  float* mean1 = sm;
  float* istd1 = sm + 256;
  float* mean2 = sm + 512;
  float* istd2 = sm + 768;
  float* qm    = sm + 1024;
  float* km    = sm + 1024 + 16384;
  int*   idxb  = (int*)(sm + 1024 + 32768);
  float* wTlep = sm + 1024 + 32768 + 256;      // 27*256 fp32

  // weight transposes
  k_tr<<<dim3(24, 8, 1), 256, 0, stream>>>(wqkv, wqkvT, 256, 768, 0, 0);
  k_tr<<<dim3(32, 8, 1), 256, 0, stream>>>(ffn_w1, w1T, 256, 1024, 0, 0);
  k_tr<<<dim3(8, 32, 1), 256, 0, stream>>>(ffn_w2, w2T, 1024, 256, 0, 0);
  k_tr<<<dim3(8, 8, 1), 256, 0, stream>>>(wo_w, woT, 256, 256, 0, 0);
  k_trw<<<1, 256, 0, stream>>>(lepe_w, wTlep);

  // ---- attention branch ----
  k_bnstats<<<256, 256, 0, stream>>>(x, mean1, istd1);
  k_lifT<<<dim3(256, 8), 256, 0, stream>>>(x, mean1, istd1, bn1_g, bn1_b, actT);
  k_gqkv<<<dim3(6, 128), 256, 0, stream>>>(actT, wqkvT, bqkv, qhead, khead, vthead, vtok);
  k_means<<<512, 256, 0, stream>>>(qhead, khead, qm, km);
  k_route<<<64, 256, 0, stream>>>(qm, km, idxb);
  k_attn_mfma<<<dim3(8, RR, 2), 256, 0, stream>>>(qhead, khead, vthead, idxb, oreg);
  k_lepe<<<4096, 256, 0, stream>>>(oreg, vtok, wTlep, actT);
  k_gwo<<<dim3(128, 8), 128, 0, stream>>>(woT, actT, bo, x, scale, out);

  // ---- FFN branch ----
  k_bnstats<<<256, 256, 0, stream>>>(out, mean2, istd2);
  k_lifT<<<dim3(256, 8), 256, 0, stream>>>(out, mean2, istd2, bn2_g, bn2_b, actT);
  k_gffn1<<<dim3(8, 128), 256, 0, stream>>>(actT, w1T, ffn_b1, hbuf);
  k_gffn2<<<dim3(128, 8), 128, 0, stream>>>(w2T, hbuf, ffn_b2, scale, out);
}

// Round 6
// 259.651 us; speedup vs baseline: 3.6149x; 1.0630x over previous
//
#include <hip/hip_runtime.h>
#include <math.h>

#define CC 256
#define LL 8192
#define RR 32
#define PPP 256
#define NTOP 4

typedef unsigned short u16;
typedef __attribute__((ext_vector_type(8))) short short8;
typedef __attribute__((ext_vector_type(4))) float f32x4;
typedef __attribute__((ext_vector_type(4))) unsigned short u16x4;

#if defined(__has_builtin)
#if __has_builtin(__builtin_amdgcn_exp2f)
#define EXP2(x) __builtin_amdgcn_exp2f(x)
#endif
#endif
#ifndef EXP2
#define EXP2(x) exp2f(x)
#endif

__device__ inline u16 f2bf(float f) {
  unsigned int b = __float_as_uint(f);
  unsigned int r = (b + 0x7FFFu + ((b >> 16) & 1u)) >> 16;
  return (u16)r;
}
__device__ inline float bf2f(u16 x) { return __uint_as_float(((unsigned int)x) << 16); }

// ---------------- BN stats ----------------
__global__ __launch_bounds__(256) void k_bnstats(const float* __restrict__ x,
                                                 float* __restrict__ mean,
                                                 float* __restrict__ istd) {
  int c = blockIdx.x, tid = threadIdx.x;
  float s = 0.f, sq = 0.f;
  for (int i = tid; i < 2 * LL / 4; i += 256) {
    int t = i >> 11, l4 = (i & 2047) * 4;
    float4 v = *(const float4*)&x[(size_t)(t * CC + c) * LL + l4];
    s += (v.x + v.y) + (v.z + v.w);
    sq += (v.x * v.x + v.y * v.y) + (v.z * v.z + v.w * v.w);
  }
  __shared__ float rs[256], rq[256];
  rs[tid] = s; rq[tid] = sq;
  __syncthreads();
  for (int off = 128; off > 0; off >>= 1) {
    if (tid < off) { rs[tid] += rs[tid + off]; rq[tid] += rq[tid + off]; }
    __syncthreads();
  }
  if (tid == 0) {
    float m = rs[0] * (1.f / (2 * LL));
    float var = rq[0] * (1.f / (2 * LL)) - m * m;
    mean[c] = m;
    istd[c] = rsqrtf(var + 1e-5f);
  }
}

// ---------------- fused BN + 2-step LIF + transpose -> actT bf16 [t][l][c] ----------------
__global__ __launch_bounds__(256) void k_lifT(const float* __restrict__ xin,
                                              const float* __restrict__ mean,
                                              const float* __restrict__ istd,
                                              const float* __restrict__ g,
                                              const float* __restrict__ b,
                                              u16* __restrict__ actT) {
  __shared__ float t0[32][33], t1[32][33];
  int l0 = blockIdx.x * 32, c0 = blockIdx.y * 32;
  int tx = threadIdx.x & 31, ty = threadIdx.x >> 5;
  for (int i = 0; i < 32; i += 8) {
    int c = c0 + ty + i;
    float m = mean[c], is = istd[c], gg = g[c], bb = b[c];
    float x0 = xin[(size_t)c * LL + l0 + tx];
    float x1 = xin[(size_t)(CC + c) * LL + l0 + tx];
    float y0 = gg * (x0 - m) * is + bb;
    float y1 = gg * (x1 - m) * is + bb;
    float v = y0 * 0.5f;
    float s0 = (v >= 1.f) ? 1.f : 0.f;
    v -= s0;
    v += (y1 - v) * 0.5f;
    float s1 = (v >= 1.f) ? 1.f : 0.f;
    t0[ty + i][tx] = s0;
    t1[ty + i][tx] = s1;
  }
  __syncthreads();
  for (int i = 0; i < 32; i += 8) {
    int l = l0 + ty + i;
    actT[(size_t)l * CC + c0 + tx] = f2bf(t0[tx][ty + i]);
    actT[(size_t)(LL + l) * CC + c0 + tx] = f2bf(t1[tx][ty + i]);
  }
}

// ---------------- fp32 [R][C] -> bf16 [C][R] transpose (weights) ----------------
__global__ __launch_bounds__(256) void k_tr(const float* __restrict__ in, u16* __restrict__ out,
                                            int R, int C, long ibs, long obs) {
  __shared__ float t[32][33];
  const float* ib = in + (size_t)blockIdx.z * ibs;
  u16* ob = out + (size_t)blockIdx.z * obs;
  int c0 = blockIdx.x * 32, r0 = blockIdx.y * 32;
  int tx = threadIdx.x & 31, ty = threadIdx.x >> 5;
  for (int i = 0; i < 32; i += 8)
    t[ty + i][tx] = ib[(size_t)(r0 + ty + i) * C + c0 + tx];
  __syncthreads();
  for (int i = 0; i < 32; i += 8)
    ob[(size_t)(c0 + ty + i) * R + r0 + tx] = f2bf(t[tx][ty + i]);
}

// ---------------- lepe weight transpose [256][27] -> fp32 [27][256] ----------------
__global__ __launch_bounds__(256) void k_trw(const float* __restrict__ w, float* __restrict__ wT) {
  int c = threadIdx.x;
  for (int tap = 0; tap < 27; ++tap) wT[tap * 256 + c] = w[c * 27 + tap];
}

// ---------------- MFMA core: D[m][n] += A[m][k]*B[n][k]^T, K-contiguous bf16 ----------------
template<int MR, int NR, int WCN>
__device__ inline void mfma_core(const u16* __restrict__ A0, int sA,
                                 const u16* __restrict__ B0, int sB,
                                 int K, f32x4 acc[MR][NR]) {
  int lane = threadIdx.x & 63;
  int w = threadIdx.x >> 6;
  int wr = w / WCN, wc = w % WCN;
  int rr = lane & 15;
  int g8 = (lane >> 4) * 8;
  const u16* Ap = A0 + (size_t)(wr * MR * 16 + rr) * sA + g8;
  const u16* Bp = B0 + (size_t)(wc * NR * 16 + rr) * sB + g8;
  for (int k0 = 0; k0 < K; k0 += 32) {
    short8 af[MR], bfr[NR];
#pragma unroll
    for (int i = 0; i < MR; ++i)
      af[i] = *(const short8*)(Ap + (size_t)i * 16 * sA + k0);
#pragma unroll
    for (int j = 0; j < NR; ++j)
      bfr[j] = *(const short8*)(Bp + (size_t)j * 16 * sB + k0);
#pragma unroll
    for (int i = 0; i < MR; ++i)
#pragma unroll
      for (int j = 0; j < NR; ++j)
        acc[i][j] = __builtin_amdgcn_mfma_f32_16x16x32_bf16(af[i], bfr[j], acc[i][j], 0, 0, 0);
  }
}

// ---------------- qkv GEMM -> bf16 per-head q(scaled)/k, transposed v; bf16 v token-major ----------------
__global__ __launch_bounds__(256) void k_gqkv(const u16* __restrict__ spkT, const u16* __restrict__ wT,
                                              const float* __restrict__ bias,
                                              u16* __restrict__ qh, u16* __restrict__ kh,
                                              u16* __restrict__ vt, u16* __restrict__ vtok) {
  f32x4 acc[4][4] = {};
  int n0 = blockIdx.x * 128, m0 = blockIdx.y * 128;
  mfma_core<4, 4, 2>(spkT + (size_t)m0 * 256, 256, wT + (size_t)n0 * 256, 256, 256, acc);
  int lane = threadIdx.x & 63, w = threadIdx.x >> 6;
  int wr = w >> 1, wc = w & 1;
  int u = lane & 15;
  const float QSC = 0.255034865f;   // 32^-0.5 * log2(e)
#pragma unroll
  for (int i = 0; i < 4; ++i) {
#pragma unroll
    for (int reg = 0; reg < 4; ++reg) {
      int token = m0 + wr * 64 + i * 16 + (lane >> 4) * 4 + reg;
      int l = token & (LL - 1), nb = token >> 13;
      int lt = l >> 10, lh = (l >> 5) & 31, lw = l & 31;
      int r = ((lt >> 2) * 4 + (lh >> 3)) * 4 + (lw >> 3);
      int p = ((lt & 3) * 8 + (lh & 7)) * 8 + (lw & 7);
      int nr = nb * RR + r;
#pragma unroll
      for (int j = 0; j < 4; ++j) {
        int ch = n0 + wc * 64 + j * 16 + u;
        float val = acc[i][j][reg] + bias[ch];
        int which = ch >> 8, c = ch & 255;
        int hh = c >> 5, dh = c & 31;
        size_t hb = ((size_t)nr * 8 + hh) * 8192;
        if (which == 0) {
          qh[hb + p * 32 + dh] = f2bf(val * QSC);
        } else if (which == 1) {
          kh[hb + p * 32 + dh] = f2bf(val);
        } else {
          u16 vb = f2bf(val);
          vt[hb + dh * 256 + p] = vb;
          vtok[(size_t)token * CC + c] = vb;
        }
      }
    }
  }
}

// ---------------- region means: block per (nr, h) ----------------
__global__ __launch_bounds__(256) void k_means(const u16* __restrict__ qh, const u16* __restrict__ kh,
                                               float* __restrict__ qm, float* __restrict__ km) {
  int nrh = blockIdx.x;               // nr*8 + h
  int nr = nrh >> 3, h = nrh & 7;
  int tid = threadIdx.x;
  int dh = tid & 31, pg = tid >> 5;   // 8 p-groups
  size_t base = (size_t)nrh * 8192;
  float sq = 0.f, sk = 0.f;
  for (int p = pg * 32; p < pg * 32 + 32; ++p) {
    sq += bf2f(qh[base + p * 32 + dh]);
    sk += bf2f(kh[base + p * 32 + dh]);
  }
  __shared__ float rq[256], rk[256];
  rq[tid] = sq; rk[tid] = sk;
  __syncthreads();
  if (pg == 0) {
#pragma unroll
    for (int g = 1; g < 8; ++g) { sq += rq[g * 32 + dh]; sk += rk[g * 32 + dh]; }
    qm[nr * 256 + h * 32 + dh] = sq * (1.f / 256);
    km[nr * 256 + h * 32 + dh] = sk * (1.f / 256);
  }
}

// ---------------- routing top-4: 8 lanes per candidate region ----------------
__global__ __launch_bounds__(256) void k_route(const float* __restrict__ qm,
                                               const float* __restrict__ km,
                                               int* __restrict__ idx) {
  int nr = blockIdx.x;
  int n = nr >> 5;
  int tid = threadIdx.x;
  int s = tid >> 3, cg = tid & 7;
  const float* qrow = qm + nr * CC;
  const float* krow = km + (n * RR + s) * CC;
  float sum = 0.f;
  for (int c = cg * 32; c < cg * 32 + 32; ++c) sum += qrow[c] * krow[c];
  sum += __shfl_xor(sum, 1);
  sum += __shfl_xor(sum, 2);
  sum += __shfl_xor(sum, 4);
  __shared__ float ar[32];
  if (cg == 0) ar[s] = sum;
  __syncthreads();
  if (tid == 0) {
    for (int t = 0; t < NTOP; ++t) {
      float best = -1e30f; int bi = 0;
      for (int ss = 0; ss < 32; ++ss)
        if (ar[ss] > best) { best = ar[ss]; bi = ss; }
      ar[bi] = -1e30f;
      idx[nr * NTOP + t] = bi;
    }
  }
}

// ---------------- MFMA flash attention: block (h, r, n), 4 waves x 64 q-rows ----------------
// Q pre-scaled by 32^-0.5*log2e -> p = exp2(s). P staged in LDS as u32 words,
// layout [nf][u][16 u32] with 16B-block XOR swizzle (block ^= (u>>1)&3).
__global__ __launch_bounds__(256) void k_attn_mfma(const u16* __restrict__ qh,
                                                   const u16* __restrict__ kh,
                                                   const u16* __restrict__ vt,
                                                   const int* __restrict__ idx,
                                                   u16* __restrict__ oreg) {
  int h = blockIdx.x, r = blockIdx.y, n = blockIdx.z;
  int nr = n * RR + r;
  int lane = threadIdx.x & 63;
  int w = threadIdx.x >> 6;
  int u = lane & 15, g = lane >> 4;
  int swz = (u >> 1) & 3;
  __shared__ __align__(16) unsigned pl[4096];   // 4 waves x [4 nf][16 u][16 u32]
  unsigned* plw = &pl[w * 1024];

  const u16* qb = qh + ((size_t)nr * 8 + h) * 8192;
  int q0 = w * 64;
  short8 qf[4];
#pragma unroll
  for (int f = 0; f < 4; ++f)
    qf[f] = *(const short8*)(qb + (size_t)(q0 + f * 16 + u) * 32 + g * 8);

  f32x4 accO[2][4] = {};
  float lsum[4] = {0.f, 0.f, 0.f, 0.f};
  const int* idxp = &idx[nr * NTOP];

  for (int ri = 0; ri < NTOP; ++ri) {
    int reg = idxp[ri];
    size_t rb = ((size_t)(n * RR + reg) * 8 + h) * 8192;
#pragma unroll 2
    for (int t = 0; t < 8; ++t) {
      int pb = t * 32;
      short8 kf0 = *(const short8*)(kh + rb + (size_t)(pb + u) * 32 + g * 8);
      short8 kf1 = *(const short8*)(kh + rb + (size_t)(pb + 16 + u) * 32 + g * 8);
      short8 vf0 = *(const short8*)(vt + rb + (size_t)u * 256 + pb + g * 8);
      short8 vf1 = *(const short8*)(vt + rb + (size_t)(16 + u) * 256 + pb + g * 8);

      f32x4 s0[4], s1[4];
      __builtin_amdgcn_s_setprio(1);
#pragma unroll
      for (int nf = 0; nf < 4; ++nf) {
        s0[nf] = __builtin_amdgcn_mfma_f32_16x16x32_bf16(kf0, qf[nf], (f32x4){0.f, 0.f, 0.f, 0.f}, 0, 0, 0);
        s1[nf] = __builtin_amdgcn_mfma_f32_16x16x32_bf16(kf1, qf[nf], (f32x4){0.f, 0.f, 0.f, 0.f}, 0, 0, 0);
      }
      __builtin_amdgcn_s_setprio(0);
#pragma unroll
      for (int nf = 0; nf < 4; ++nf) {
#pragma unroll
        for (int mf = 0; mf < 2; ++mf) {
          f32x4 sv = mf ? s1[nf] : s0[nf];
          float p0 = EXP2(sv[0]);
          float p1 = EXP2(sv[1]);
          float p2 = EXP2(sv[2]);
          float p3 = EXP2(sv[3]);
          lsum[nf] += (p0 + p1) + (p2 + p3);
          unsigned wA, wB;
          asm("v_cvt_pk_bf16_f32 %0, %1, %2" : "=v"(wA) : "v"(p0), "v"(p1));
          asm("v_cvt_pk_bf16_f32 %0, %1, %2" : "=v"(wB) : "v"(p2), "v"(p3));
          int bidx = (mf * 2 + (g >> 1)) ^ swz;
          *(uint2*)&plw[nf * 256 + u * 16 + bidx * 4 + (g & 1) * 2] = make_uint2(wA, wB);
        }
      }
      __builtin_amdgcn_s_setprio(1);
#pragma unroll
      for (int nf = 0; nf < 4; ++nf) {
        short8 pf = *(const short8*)&plw[nf * 256 + u * 16 + ((g ^ swz) << 2)];
        accO[0][nf] = __builtin_amdgcn_mfma_f32_16x16x32_bf16(vf0, pf, accO[0][nf], 0, 0, 0);
        accO[1][nf] = __builtin_amdgcn_mfma_f32_16x16x32_bf16(vf1, pf, accO[1][nf], 0, 0, 0);
      }
      __builtin_amdgcn_s_setprio(0);
    }
  }

#pragma unroll
  for (int nf = 0; nf < 4; ++nf) {
    lsum[nf] += __shfl_xor(lsum[nf], 16);
    lsum[nf] += __shfl_xor(lsum[nf], 32);
    float inv = 1.f / lsum[nf];
    int q = q0 + nf * 16 + u;
    int z = (((r >> 4) & 1) << 2) | ((q >> 6) & 3);
    int y = (((r >> 2) & 3) << 3) | ((q >> 3) & 7);
    int xx = ((r & 3) << 3) | (q & 7);
    int l = (z << 10) | (y << 5) | xx;
    u16* ob = &oreg[((size_t)(n * LL + l)) * CC + h * 32];
#pragma unroll
    for (int mf = 0; mf < 2; ++mf) {
      f32x4 o = mf ? accO[1][nf] : accO[0][nf];
      float a0 = o[0] * inv, a1 = o[1] * inv, a2 = o[2] * inv, a3 = o[3] * inv;
      unsigned w0, w1;
      asm("v_cvt_pk_bf16_f32 %0, %1, %2" : "=v"(w0) : "v"(a0), "v"(a1));
      asm("v_cvt_pk_bf16_f32 %0, %1, %2" : "=v"(w1) : "v"(a2), "v"(a3));
      *(uint2*)&ob[mf * 16 + g * 4] = make_uint2(w0, w1);
    }
  }
}

// ---------------- LEPE stencil, token-major bf16, 4 voxels/block ----------------
__global__ __launch_bounds__(256) void k_lepe(const u16* __restrict__ oreg,
                                              const u16* __restrict__ vtok,
                                              const float* __restrict__ wT,
                                              u16* __restrict__ otok) {
  int vox = threadIdx.x >> 6;
  int b = blockIdx.x * 4 + vox;       // n*8192 + l
  int l = b & (LL - 1);
  int lt = l >> 10, lh = (l >> 5) & 31, lw = l & 31;
  int c4 = (threadIdx.x & 63) * 4;
  const u16* vb = vtok + (size_t)b * CC + c4;
  float lx = 0.f, ly = 0.f, lz = 0.f, lww = 0.f;
#pragma unroll
  for (int dz = -1; dz <= 1; ++dz) {
#pragma unroll
    for (int dy = -1; dy <= 1; ++dy) {
#pragma unroll
      for (int dx = -1; dx <= 1; ++dx) {
        int z = lt + dz, y = lh + dy, xx = lw + dx;
        if (z >= 0 && z < 8 && y >= 0 && y < 32 && xx >= 0 && xx < 32) {
          int tap = ((dz + 1) * 3 + (dy + 1)) * 3 + (dx + 1);
          long off = (long)(dz * 1024 + dy * 32 + dx) * CC;
          float4 w4 = *(const float4*)&wT[tap * 256 + c4];
          u16x4 v4 = *(const u16x4*)&vb[off];
          lx = fmaf(w4.x, bf2f(v4[0]), lx);
          ly = fmaf(w4.y, bf2f(v4[1]), ly);
          lz = fmaf(w4.z, bf2f(v4[2]), lz);
          lww = fmaf(w4.w, bf2f(v4[3]), lww);
        }
      }
    }
  }
  u16x4 a4 = *(const u16x4*)&oreg[(size_t)b * CC + c4];
  *(u16x4*)&otok[(size_t)b * CC + c4] =
      (u16x4){f2bf(bf2f(a4[0]) + lx), f2bf(bf2f(a4[1]) + ly),
              f2bf(bf2f(a4[2]) + lz), f2bf(bf2f(a4[3]) + lww)};
}

// ---------------- FFN1 GEMM -> GELU -> hbuf bf16 ----------------
__global__ __launch_bounds__(256) void k_gffn1(const u16* __restrict__ sT, const u16* __restrict__ wT,
                                               const float* __restrict__ bias, u16* __restrict__ hbuf) {
  f32x4 acc[4][4] = {};
  int n0 = blockIdx.x * 128, m0 = blockIdx.y * 128;
  mfma_core<4, 4, 2>(sT + (size_t)m0 * 256, 256, wT + (size_t)n0 * 256, 256, 256, acc);
  int lane = threadIdx.x & 63, w = threadIdx.x >> 6;
  int wr = w >> 1, wc = w & 1;
#pragma unroll
  for (int i = 0; i < 4; ++i) {
#pragma unroll
    for (int reg = 0; reg < 4; ++reg) {
      int token = m0 + wr * 64 + i * 16 + (lane >> 4) * 4 + reg;
#pragma unroll
      for (int j = 0; j < 4; ++j) {
        int ch = n0 + wc * 64 + j * 16 + (lane & 15);
        float z = acc[i][j][reg] + bias[ch];
        float gel = 0.5f * z * (1.f + erff(z * 0.70710678118654752f));
        hbuf[(size_t)token * 1024 + ch] = f2bf(gel);
      }
    }
  }
}

// ---------------- FFN2 GEMM (output-transposed): out[t][c][l] += (W2^T h + b2)*sc ----------------
__global__ __launch_bounds__(128) void k_gffn2(const u16* __restrict__ w2T, const u16* __restrict__ hb,
                                               const float* __restrict__ bias, const float* __restrict__ scale,
                                               float* __restrict__ out) {
  f32x4 acc[2][4] = {};
  int n0 = blockIdx.x * 128, m0 = blockIdx.y * 32;
  mfma_core<2, 4, 2>(w2T + (size_t)m0 * 1024, 1024, hb + (size_t)n0 * 1024, 1024, 1024, acc);
  int lane = threadIdx.x & 63, wc = threadIdx.x >> 6;
  float sc = scale[0];
#pragma unroll
  for (int i = 0; i < 2; ++i) {
#pragma unroll
    for (int reg = 0; reg < 4; ++reg) {
      int ch = m0 + i * 16 + (lane >> 4) * 4 + reg;
      float bb = bias[ch];
#pragma unroll
      for (int j = 0; j < 4; ++j) {
        int token = n0 + wc * 64 + j * 16 + (lane & 15);
        int t = token >> 13, l = token & (LL - 1);
        size_t oi = ((size_t)t * CC + ch) * LL + l;
        out[oi] += (acc[i][j][reg] + bb) * sc;
      }
    }
  }
}

// ---------------- Wo GEMM (output-transposed): out[t][c][l] = x + (Wo^T a + bo)*sc ----------------
__global__ __launch_bounds__(128) void k_gwo(const u16* __restrict__ woT, const u16* __restrict__ atok,
                                             const float* __restrict__ bias, const float* __restrict__ xin,
                                             const float* __restrict__ scale, float* __restrict__ out) {
  f32x4 acc[2][4] = {};
  int n0 = blockIdx.x * 128, m0 = blockIdx.y * 32;
  mfma_core<2, 4, 2>(woT + (size_t)m0 * 256, 256, atok + (size_t)n0 * 256, 256, 256, acc);
  int lane = threadIdx.x & 63, wc = threadIdx.x >> 6;
  float sc = scale[0];
#pragma unroll
  for (int i = 0; i < 2; ++i) {
#pragma unroll
    for (int reg = 0; reg < 4; ++reg) {
      int ch = m0 + i * 16 + (lane >> 4) * 4 + reg;
      float bb = bias[ch];
#pragma unroll
      for (int j = 0; j < 4; ++j) {
        int token = n0 + wc * 64 + j * 16 + (lane & 15);
        int t = token >> 13, l = token & (LL - 1);
        size_t oi = ((size_t)t * CC + ch) * LL + l;
        out[oi] = xin[oi] + (acc[i][j][reg] + bb) * sc;
      }
    }
  }
}

extern "C" void kernel_launch(void* const* d_in, const int* in_sizes, int n_in,
                              void* d_out, int out_size, void* d_ws, size_t ws_size,
                              hipStream_t stream) {
  const float* x      = (const float*)d_in[0];
  const float* bn1_g  = (const float*)d_in[1];
  const float* bn1_b  = (const float*)d_in[2];
  const float* wqkv   = (const float*)d_in[3];
  const float* bqkv   = (const float*)d_in[4];
  const float* lepe_w = (const float*)d_in[5];
  const float* wo_w   = (const float*)d_in[6];
  const float* bo     = (const float*)d_in[7];
  const float* bn2_g  = (const float*)d_in[8];
  const float* bn2_b  = (const float*)d_in[9];
  const float* ffn_w1 = (const float*)d_in[10];
  const float* ffn_b1 = (const float*)d_in[11];
  const float* ffn_w2 = (const float*)d_in[12];
  const float* ffn_b2 = (const float*)d_in[13];
  const float* scale  = (const float*)d_in[14];
  float* out = (float*)d_out;

  float* ws    = (float*)d_ws;
  u16*   actT  = (u16*)(ws + 4194304);         // 4M u16: spkT / otok / s2T
  u16*   qhead = (u16*)(ws + 6291456);         // 4M u16 (pre-scaled)
  u16*   khead = (u16*)(ws + 8388608);         // 4M u16
  u16*   vthead= (u16*)(ws + 10485760);        // 4M u16
  u16*   vtok  = (u16*)(ws + 12582912);        // 4M u16 (token-major bf16 v)
  u16*   oreg  = (u16*)(ws + 16777216);        // 4M u16 (token-major attn out)
  u16*   hbuf  = (u16*)(ws + 6291456);         // 16M u16, overlaps qhead..vtok (dead in FFN)
  u16*   wqkvT = (u16*)(ws + 20971520);
  u16*   w1T   = (u16*)(ws + 21069824);
  u16*   w2T   = (u16*)(ws + 21200896);
  u16*   woT   = (u16*)(ws + 21331968);
  float* sm    = ws + 21364736;
  float* mean1 = sm;
  float* istd1 = sm + 256;
  float* mean2 = sm + 512;
  float* istd2 = sm + 768;
  float* qm    = sm + 1024;
  float* km    = sm + 1024 + 16384;
  int*   idxb  = (int*)(sm + 1024 + 32768);
  float* wTlep = sm + 1024 + 32768 + 256;      // 27*256 fp32

  // weight transposes
  k_tr<<<dim3(24, 8, 1), 256, 0, stream>>>(wqkv, wqkvT, 256, 768, 0, 0);
  k_tr<<<dim3(32, 8, 1), 256, 0, stream>>>(ffn_w1, w1T, 256, 1024, 0, 0);
  k_tr<<<dim3(8, 32, 1), 256, 0, stream>>>(ffn_w2, w2T, 1024, 256, 0, 0);
  k_tr<<<dim3(8, 8, 1), 256, 0, stream>>>(wo_w, woT, 256, 256, 0, 0);
  k_trw<<<1, 256, 0, stream>>>(lepe_w, wTlep);

  // ---- attention branch ----
  k_bnstats<<<256, 256, 0, stream>>>(x, mean1, istd1);
  k_lifT<<<dim3(256, 8), 256, 0, stream>>>(x, mean1, istd1, bn1_g, bn1_b, actT);
  k_gqkv<<<dim3(6, 128), 256, 0, stream>>>(actT, wqkvT, bqkv, qhead, khead, vthead, vtok);
  k_means<<<512, 256, 0, stream>>>(qhead, khead, qm, km);
  k_route<<<64, 256, 0, stream>>>(qm, km, idxb);
  k_attn_mfma<<<dim3(8, RR, 2), 256, 0, stream>>>(qhead, khead, vthead, idxb, oreg);
  k_lepe<<<4096, 256, 0, stream>>>(oreg, vtok, wTlep, actT);
  k_gwo<<<dim3(128, 8), 128, 0, stream>>>(woT, actT, bo, x, scale, out);

  // ---- FFN branch ----
  k_bnstats<<<256, 256, 0, stream>>>(out, mean2, istd2);
  k_lifT<<<dim3(256, 8), 256, 0, stream>>>(out, mean2, istd2, bn2_g, bn2_b, actT);
  k_gffn1<<<dim3(8, 128), 256, 0, stream>>>(actT, w1T, ffn_b1, hbuf);
  k_gffn2<<<dim3(128, 8), 128, 0, stream>>>(w2T, hbuf, ffn_b2, scale, out);
}